// Round 2
// baseline (1190.016 us; speedup 1.0000x reference)
//
#include <hip/hip_runtime.h>
#include <math.h>

#define N_NODES 50000
#define N_EDGES 800000

__device__ __forceinline__ float elu_f(float x) { return x > 0.f ? x : expm1f(x); }

// ---------------- edge pass 1: score, segment-max (int-cmp trick), degree ----
__global__ __launch_bounds__(256)
void k_score(const float* __restrict__ off2, const int* __restrict__ dst,
             float* __restrict__ score, int* __restrict__ mx_i, int* __restrict__ deg) {
    int e = blockIdx.x * 256 + threadIdx.x;
    if (e >= N_EDGES) return;
    float2 o = ((const float2*)off2)[e];
    float s = 1.f / (fabsf(o.x) + fabsf(o.y) + 0.001f);   // s > 0 always
    score[e] = s;
    int d = dst[e];
    atomicMax(&mx_i[d], __float_as_int(s));               // positive floats: int order == float order
    atomicAdd(&deg[d], 1);
}

// ---------------- single-block exclusive scan over degrees -------------------
__global__ __launch_bounds__(1024)
void k_scan(const int* __restrict__ deg, int* __restrict__ rs, int* __restrict__ cur) {
    __shared__ int lds[1024];
    __shared__ int carry_s;
    const int tid = threadIdx.x;
    if (tid == 0) carry_s = 0;
    __syncthreads();
    for (int base = 0; base < N_NODES; base += 1024) {
        int i = base + tid;
        int v = (i < N_NODES) ? deg[i] : 0;
        lds[tid] = v;
        __syncthreads();
        #pragma unroll
        for (int off = 1; off < 1024; off <<= 1) {
            int t = (tid >= off) ? lds[tid - off] : 0;
            __syncthreads();
            lds[tid] += t;
            __syncthreads();
        }
        int carry = carry_s;
        if (i < N_NODES) {
            int excl = carry + lds[tid] - v;
            rs[i]  = excl;
            cur[i] = excl;
        }
        int tot = lds[1023];
        __syncthreads();
        if (tid == 0) carry_s = carry + tot;
        __syncthreads();
    }
    if (tid == 0) rs[N_NODES] = carry_s;
}

// ---------------- edge pass 2: exp(score - mx[dst]), segment-sum -------------
__global__ __launch_bounds__(256)
void k_exp(const float* __restrict__ score, const int* __restrict__ dst,
           const float* __restrict__ mx, float* __restrict__ ex, float* __restrict__ denom) {
    int e = blockIdx.x * 256 + threadIdx.x;
    if (e >= N_EDGES) return;
    int d = dst[e];
    float v = expf(score[e] - mx[d]);
    ex[e] = v;
    atomicAdd(&denom[d], v);
}

// ---------------- CSR fill ---------------------------------------------------
__global__ __launch_bounds__(256)
void k_fill(const int* __restrict__ dst, int* __restrict__ cur, int* __restrict__ eid) {
    int e = blockIdx.x * 256 + threadIdx.x;
    if (e >= N_EDGES) return;
    int d = dst[e];
    int p = atomicAdd(&cur[d], 1);
    eid[p] = e;
}

// ---------------- fused edge-MLP + softmax-weight + gather-aggregate ---------
// One wave per dst node (grid-stride). Lane j (0..63) owns output column j:
//   - kW2 column j (128 floats) lives in registers
//   - per edge: lanes cooperatively compute h[128] (2 each), broadcast via LDS
//     (same-address b128 reads -> conflict-free broadcast),
//     each lane reduces kw_j = sum_i h_i * W2[i][j] + b_j in registers,
//     agg_j accumulated in a register; single store per node. No fp32 atomics.
__global__ __launch_bounds__(256)
void k_gather(const float* __restrict__ off2, const int* __restrict__ src,
              const int* __restrict__ eid, const int* __restrict__ rs,
              const float* __restrict__ ex, const float* __restrict__ denom,
              const float* __restrict__ feat,
              const float* __restrict__ kW1, const float* __restrict__ kb1,
              const float* __restrict__ kW2, const float* __restrict__ kb2,
              float* __restrict__ agg) {
    __shared__ float hsh_all[4][128];
    const int lane = threadIdx.x & 63;
    const int wav  = threadIdx.x >> 6;
    float* hsh = hsh_all[wav];
    const int gw = blockIdx.x * 4 + wav;
    const int nw = gridDim.x * 4;

    float w2r[128];
    #pragma unroll
    for (int i = 0; i < 128; ++i) w2r[i] = kW2[i * 64 + lane];
    const float a0 = kW1[2 * lane],       a1 = kW1[2 * lane + 1];
    const float b0 = kW1[128 + 2 * lane], b1 = kW1[128 + 2 * lane + 1];
    const float c0 = kb1[2 * lane],       c1 = kb1[2 * lane + 1];
    const float bias2 = kb2[lane];

    for (int n = gw; n < N_NODES; n += nw) {
        const int p0 = rs[n], p1 = rs[n + 1];
        float aggj = 0.f;
        if (p1 > p0) {
            const float dinv = 1.f / denom[n];
            for (int p = p0; p < p1; ++p) {
                const int e = eid[p];
                float2 o = ((const float2*)off2)[e];
                float h0 = elu_f(fmaf(o.y, b0, fmaf(o.x, a0, c0)));
                float h1 = elu_f(fmaf(o.y, b1, fmaf(o.x, a1, c1)));
                hsh[2 * lane]     = h0;
                hsh[2 * lane + 1] = h1;
                __builtin_amdgcn_s_waitcnt(0);       // drain ds_write (wave-lockstep, no barrier needed)
                __builtin_amdgcn_sched_barrier(0);   // pin: no reordering across the wait (rule #18)
                float acc0 = bias2, acc1 = 0.f;
                #pragma unroll
                for (int iq = 0; iq < 32; iq += 2) {
                    float4 ha = *(const float4*)&hsh[iq * 4];
                    float4 hb = *(const float4*)&hsh[iq * 4 + 4];
                    acc0 = fmaf(ha.x, w2r[iq * 4 + 0], acc0);
                    acc0 = fmaf(ha.y, w2r[iq * 4 + 1], acc0);
                    acc0 = fmaf(ha.z, w2r[iq * 4 + 2], acc0);
                    acc0 = fmaf(ha.w, w2r[iq * 4 + 3], acc0);
                    acc1 = fmaf(hb.x, w2r[iq * 4 + 4], acc1);
                    acc1 = fmaf(hb.y, w2r[iq * 4 + 5], acc1);
                    acc1 = fmaf(hb.z, w2r[iq * 4 + 6], acc1);
                    acc1 = fmaf(hb.w, w2r[iq * 4 + 7], acc1);
                }
                float kw = acc0 + acc1;
                float we = ex[e] * dinv;
                float f  = feat[src[e] * 64 + lane];
                aggj = fmaf(f, we * kw, aggj);
                __builtin_amdgcn_s_waitcnt(0);       // ds_reads done before next iter's ds_write
                __builtin_amdgcn_sched_barrier(0);
            }
        }
        agg[n * 64 + lane] = aggj;
    }
}

// ---------------- generic fused GEMM: Y = act(X1@W1 [+ X2@W2] + b) -----------
// 256 threads = 4 waves; block tile 64 rows x 128 cols; wave handles 16 rows,
// lane j covers cols j and j+64. X staged in LDS (b128 broadcast reads),
// W streamed from global (L1/L2 resident). VALU-bound by construction.
template<int K1, int K2, bool ELU>
__global__ __launch_bounds__(256)
void k_gemm(const float* __restrict__ X1, const float* __restrict__ W1,
            const float* __restrict__ X2, const float* __restrict__ W2,
            const float* __restrict__ bias, float* __restrict__ Y, int nrows) {
    constexpr int KT  = K1 + K2;
    constexpr int KQT = KT / 4;
    constexpr int KQ1 = K1 / 4;
    __shared__ float xs[64 * KT];
    const int tid  = threadIdx.x;
    const int row0 = blockIdx.x * 64;

    for (int idx = tid; idx < 64 * KQT; idx += 256) {
        int r  = idx / KQT;
        int kq = idx - r * KQT;
        int row = row0 + r;
        float4 v = make_float4(0.f, 0.f, 0.f, 0.f);
        if (row < nrows) {
            if (K2 == 0 || kq < KQ1) v = *(const float4*)&X1[row * K1 + kq * 4];
            else                     v = *(const float4*)&X2[row * K2 + (kq - KQ1) * 4];
        }
        *(float4*)&xs[r * KT + kq * 4] = v;
    }
    __syncthreads();

    const int lane  = tid & 63;
    const int wv    = tid >> 6;
    const int rbase = wv * 16;
    float accA[16], accB[16];
    const float bA = bias[lane], bB = bias[lane + 64];
    #pragma unroll
    for (int r = 0; r < 16; ++r) { accA[r] = bA; accB[r] = bB; }

    #pragma unroll 1
    for (int k = 0; k < K1; k += 4) {
        float wa0 = W1[(k + 0) * 128 + lane];
        float wa1 = W1[(k + 1) * 128 + lane];
        float wa2 = W1[(k + 2) * 128 + lane];
        float wa3 = W1[(k + 3) * 128 + lane];
        float wb0 = W1[(k + 0) * 128 + 64 + lane];
        float wb1 = W1[(k + 1) * 128 + 64 + lane];
        float wb2 = W1[(k + 2) * 128 + 64 + lane];
        float wb3 = W1[(k + 3) * 128 + 64 + lane];
        #pragma unroll
        for (int r = 0; r < 16; ++r) {
            float4 x = *(const float4*)&xs[(rbase + r) * KT + k];
            accA[r] = fmaf(x.x, wa0, accA[r]);
            accA[r] = fmaf(x.y, wa1, accA[r]);
            accA[r] = fmaf(x.z, wa2, accA[r]);
            accA[r] = fmaf(x.w, wa3, accA[r]);
            accB[r] = fmaf(x.x, wb0, accB[r]);
            accB[r] = fmaf(x.y, wb1, accB[r]);
            accB[r] = fmaf(x.z, wb2, accB[r]);
            accB[r] = fmaf(x.w, wb3, accB[r]);
        }
    }
    if constexpr (K2 > 0) {
        #pragma unroll 1
        for (int k = 0; k < K2; k += 4) {
            float wa0 = W2[(k + 0) * 128 + lane];
            float wa1 = W2[(k + 1) * 128 + lane];
            float wa2 = W2[(k + 2) * 128 + lane];
            float wa3 = W2[(k + 3) * 128 + lane];
            float wb0 = W2[(k + 0) * 128 + 64 + lane];
            float wb1 = W2[(k + 1) * 128 + 64 + lane];
            float wb2 = W2[(k + 2) * 128 + 64 + lane];
            float wb3 = W2[(k + 3) * 128 + 64 + lane];
            #pragma unroll
            for (int r = 0; r < 16; ++r) {
                float4 x = *(const float4*)&xs[(rbase + r) * KT + K1 + k];
                accA[r] = fmaf(x.x, wa0, accA[r]);
                accA[r] = fmaf(x.y, wa1, accA[r]);
                accA[r] = fmaf(x.z, wa2, accA[r]);
                accA[r] = fmaf(x.w, wa3, accA[r]);
                accB[r] = fmaf(x.x, wb0, accB[r]);
                accB[r] = fmaf(x.y, wb1, accB[r]);
                accB[r] = fmaf(x.z, wb2, accB[r]);
                accB[r] = fmaf(x.w, wb3, accB[r]);
            }
        }
    }

    #pragma unroll
    for (int r = 0; r < 16; ++r) {
        int row = row0 + rbase + r;
        if (row < nrows) {
            float yA = accA[r], yB = accB[r];
            if (ELU) { yA = elu_f(yA); yB = elu_f(yB); }
            Y[row * 128 + lane]      = yA;
            Y[row * 128 + 64 + lane] = yB;
        }
    }
}

// -----------------------------------------------------------------------------
extern "C" void kernel_launch(void* const* d_in, const int* in_sizes, int n_in,
                              void* d_out, int out_size, void* d_ws, size_t ws_size,
                              hipStream_t stream) {
    (void)in_sizes; (void)n_in; (void)out_size; (void)ws_size;
    const float* feat = (const float*)d_in[0];
    const float* off2 = (const float*)d_in[1];
    const int*   src  = (const int*)d_in[2];
    const int*   dst  = (const int*)d_in[3];
    const float* kW1  = (const float*)d_in[4];
    const float* kb1  = (const float*)d_in[5];
    const float* kW2  = (const float*)d_in[6];
    const float* kb2  = (const float*)d_in[7];
    const float* sW1  = (const float*)d_in[8];
    const float* sb1  = (const float*)d_in[9];
    const float* sW2  = (const float*)d_in[10];
    const float* sb2  = (const float*)d_in[11];
    const float* mW1  = (const float*)d_in[12];
    const float* mb1  = (const float*)d_in[13];
    const float* mW2  = (const float*)d_in[14];
    const float* mb2  = (const float*)d_in[15];
    const float* mW3  = (const float*)d_in[16];
    const float* mb3  = (const float*)d_in[17];
    const float* mW4  = (const float*)d_in[18];
    const float* mb4  = (const float*)d_in[19];

    char* ws = (char*)d_ws;
    size_t off = 0;
    auto alloc = [&](size_t nelem) -> void* {
        void* p = ws + off;
        off += ((nelem * 4 + 255) / 256) * 256;
        return p;
    };
    float* score = (float*)alloc(N_EDGES);
    float* ex    = (float*)alloc(N_EDGES);
    int*   eid   = (int*)alloc(N_EDGES);
    float* mx    = (float*)alloc(N_NODES);   // zeroed (scores > 0, so 0 acts as -inf)
    float* denom = (float*)alloc(N_NODES);   // zeroed
    int*   deg   = (int*)alloc(N_NODES);     // zeroed
    int*   rs    = (int*)alloc(N_NODES + 8);
    int*   cur   = (int*)alloc(N_NODES);
    float* agg   = (float*)alloc((size_t)N_NODES * 64);
    float* bufA  = (float*)alloc((size_t)N_NODES * 128);
    float* bufB  = (float*)alloc((size_t)N_NODES * 128);

    // zero mx..deg in one shot (contiguous-with-padding region)
    size_t zbytes = (size_t)((char*)(deg + N_NODES) - (char*)mx);
    hipMemsetAsync(mx, 0, zbytes, stream);

    const int EB = (N_EDGES + 255) / 256;     // 3125
    const int GB = (N_NODES + 63) / 64;       // 782

    k_score<<<EB, 256, 0, stream>>>(off2, dst, score, (int*)mx, deg);
    k_scan<<<1, 1024, 0, stream>>>(deg, rs, cur);
    k_exp<<<EB, 256, 0, stream>>>(score, dst, mx, ex, denom);
    k_fill<<<EB, 256, 0, stream>>>(dst, cur, eid);
    k_gather<<<2048, 256, 0, stream>>>(off2, src, eid, rs, ex, denom, feat,
                                       kW1, kb1, kW2, kb2, agg);

    // self branch
    k_gemm<64, 0, true ><<<GB, 256, 0, stream>>>(feat, sW1, nullptr, nullptr, sb1, bufA, N_NODES);
    k_gemm<128, 0, false><<<GB, 256, 0, stream>>>(bufA, sW2, nullptr, nullptr, sb2, bufB, N_NODES);
    // MLP head: concat handled by split-K over mW1 rows [0:64) and [64:192)
    k_gemm<64, 128, true><<<GB, 256, 0, stream>>>(agg, mW1, bufB, mW1 + 64 * 128, mb1, bufA, N_NODES);
    k_gemm<128, 0, true ><<<GB, 256, 0, stream>>>(bufA, mW2, nullptr, nullptr, mb2, bufB, N_NODES);
    k_gemm<128, 0, true ><<<GB, 256, 0, stream>>>(bufB, mW3, nullptr, nullptr, mb3, bufA, N_NODES);
    k_gemm<128, 0, false><<<GB, 256, 0, stream>>>(bufA, mW4, nullptr, nullptr, mb4, (float*)d_out, N_NODES);
}

// Round 3
// 856.670 us; speedup vs baseline: 1.3891x; 1.3891x over previous
//
#include <hip/hip_runtime.h>
#include <hip/hip_bf16.h>
#include <math.h>

#define N_NODES 50000
#define N_EDGES 800000

__device__ __forceinline__ float elu_f(float x) { return x > 0.f ? x : expm1f(x); }
__device__ __forceinline__ float edge_score(float2 o) {
    return 1.f / (fabsf(o.x) + fabsf(o.y) + 0.001f);   // > 0 always
}

// ---------------- degree histogram ------------------------------------------
__global__ __launch_bounds__(256)
void k_deg(const int* __restrict__ dst, int* __restrict__ deg) {
    int e = blockIdx.x * 256 + threadIdx.x;
    if (e >= N_EDGES) return;
    atomicAdd(&deg[dst[e]], 1);
}

// ---------------- single-block exclusive scan over degrees -------------------
__global__ __launch_bounds__(1024)
void k_scan(const int* __restrict__ deg, int* __restrict__ rs, int* __restrict__ cur) {
    __shared__ int lds[1024];
    __shared__ int carry_s;
    const int tid = threadIdx.x;
    if (tid == 0) carry_s = 0;
    __syncthreads();
    for (int base = 0; base < N_NODES; base += 1024) {
        int i = base + tid;
        int v = (i < N_NODES) ? deg[i] : 0;
        lds[tid] = v;
        __syncthreads();
        #pragma unroll
        for (int off = 1; off < 1024; off <<= 1) {
            int t = (tid >= off) ? lds[tid - off] : 0;
            __syncthreads();
            lds[tid] += t;
            __syncthreads();
        }
        int carry = carry_s;
        if (i < N_NODES) {
            int excl = carry + lds[tid] - v;
            rs[i]  = excl;
            cur[i] = excl;
        }
        int tot = lds[1023];
        __syncthreads();
        if (tid == 0) carry_s = carry + tot;
        __syncthreads();
    }
    if (tid == 0) rs[N_NODES] = carry_s;
}

// ---------------- CSR fill ---------------------------------------------------
__global__ __launch_bounds__(256)
void k_fill(const int* __restrict__ dst, int* __restrict__ cur, int* __restrict__ eid) {
    int e = blockIdx.x * 256 + threadIdx.x;
    if (e >= N_EDGES) return;
    int p = atomicAdd(&cur[dst[e]], 1);
    eid[p] = e;
}

// ---------------- per-edge kernel-weight GEMM --------------------------------
// Block = 64 edges. Phase 1: H[128][64] in LDS (wave q computes h-rows q*32..).
// Phase 2: 64x64 tile GEMM, thread owns 4 edges x 4 cols, K=128.
// kW2 streamed from L1 (32 KB, block-wide reuse). VALU-bound: 16 fma per
// ds_read_b128 per lane.
template<typename KWT>
__global__ __launch_bounds__(256)
void k_kw(const float* __restrict__ off2,
          const float* __restrict__ kW1, const float* __restrict__ kb1,
          const float* __restrict__ kW2, const float* __restrict__ kb2,
          KWT* __restrict__ kwbuf) {
    __shared__ float Hs[128 * 64];
    const int t  = threadIdx.x;
    const int eb = blockIdx.x * 64;
    {
        const int le = t & 63, q = t >> 6;
        float2 o = ((const float2*)off2)[eb + le];
        #pragma unroll
        for (int ii = 0; ii < 32; ++ii) {
            int i = q * 32 + ii;
            float h = elu_f(fmaf(o.y, kW1[128 + i], fmaf(o.x, kW1[i], kb1[i])));
            Hs[i * 64 + le] = h;
        }
    }
    __syncthreads();

    const int j0 = (t & 15) * 4;
    const int e0 = (t >> 4) * 4;
    float c[4][4];
    #pragma unroll
    for (int a = 0; a < 4; ++a)
        #pragma unroll
        for (int b = 0; b < 4; ++b) c[a][b] = 0.f;

    #pragma unroll 4
    for (int i = 0; i < 128; ++i) {
        float4 hh = *(const float4*)&Hs[i * 64 + e0];
        float4 ww = *(const float4*)&kW2[i * 64 + j0];
        const float ha[4] = {hh.x, hh.y, hh.z, hh.w};
        const float wb[4] = {ww.x, ww.y, ww.z, ww.w};
        #pragma unroll
        for (int a = 0; a < 4; ++a)
            #pragma unroll
            for (int b = 0; b < 4; ++b)
                c[a][b] = fmaf(ha[a], wb[b], c[a][b]);
    }

    float4 bb = *(const float4*)&kb2[j0];
    const float bias4[4] = {bb.x, bb.y, bb.z, bb.w};
    #pragma unroll
    for (int a = 0; a < 4; ++a) {
        if constexpr (sizeof(KWT) == 4) {
            float4 v = make_float4(c[a][0] + bias4[0], c[a][1] + bias4[1],
                                   c[a][2] + bias4[2], c[a][3] + bias4[3]);
            *(float4*)&((float*)kwbuf)[(size_t)(eb + e0 + a) * 64 + j0] = v;
        } else {
            __hip_bfloat16* kb = (__hip_bfloat16*)kwbuf;
            #pragma unroll
            for (int b = 0; b < 4; ++b)
                kb[(size_t)(eb + e0 + a) * 64 + j0 + b] = __float2bfloat16(c[a][b] + bias4[b]);
        }
    }
}

// ---------------- per-node softmax + gather-aggregate ------------------------
// One wave per dst node. Softmax recomputed in-wave from off2 (no atomics,
// no score/ex/denom buffers). Then serial edge loop: 2 coalesced 256B row
// loads + 1 fma per edge; single store per node.
template<typename KWT>
__global__ __launch_bounds__(256)
void k_agg(const float* __restrict__ off2, const int* __restrict__ src,
           const int* __restrict__ eid, const int* __restrict__ rs,
           const float* __restrict__ feat, const KWT* __restrict__ kwbuf,
           float* __restrict__ agg) {
    const int lane = threadIdx.x & 63;
    const int wav  = threadIdx.x >> 6;
    const int gw   = blockIdx.x * 4 + wav;
    const int nw   = gridDim.x * 4;

    for (int n = gw; n < N_NODES; n += nw) {
        const int p0 = rs[n], p1 = rs[n + 1];
        if (p0 == p1) { agg[(size_t)n * 64 + lane] = 0.f; continue; }

        float mx = 0.f;   // scores are strictly positive
        for (int p = p0 + lane; p < p1; p += 64) {
            float2 o = ((const float2*)off2)[eid[p]];
            mx = fmaxf(mx, edge_score(o));
        }
        #pragma unroll
        for (int d = 32; d; d >>= 1) mx = fmaxf(mx, __shfl_xor(mx, d));

        float sm = 0.f;
        for (int p = p0 + lane; p < p1; p += 64) {
            float2 o = ((const float2*)off2)[eid[p]];
            sm += expf(edge_score(o) - mx);
        }
        #pragma unroll
        for (int d = 32; d; d >>= 1) sm += __shfl_xor(sm, d);
        const float dinv = 1.f / sm;

        float aggj = 0.f;
        for (int p = p0; p < p1; ++p) {
            const int e = eid[p];
            float2 o = ((const float2*)off2)[e];
            float wgt = expf(edge_score(o) - mx) * dinv;
            float f = feat[(size_t)src[e] * 64 + lane];
            float kv;
            if constexpr (sizeof(KWT) == 4) kv = ((const float*)kwbuf)[(size_t)e * 64 + lane];
            else kv = __bfloat162float(((const __hip_bfloat16*)kwbuf)[(size_t)e * 64 + lane]);
            aggj = fmaf(f * wgt, kv, aggj);
        }
        agg[(size_t)n * 64 + lane] = aggj;
    }
}

// ---------------- 64-row x 128-col GEMM tile from LDS ------------------------
// 4 waves; wave wv handles rows wv*16..+15; lane j covers cols j and j+64.
// X rows read as same-address ds_read_b128 broadcasts (conflict-free),
// W streamed from global (L1/L2-resident, block-wide reuse).
template<int K, int LDX>
__device__ __forceinline__
void gemm_tile(const float* xs_, const float* __restrict__ W,
               const float* __restrict__ bias, int lane, int rbase,
               float accA[16], float accB[16]) {
    const float bA = bias[lane], bB = bias[lane + 64];
    #pragma unroll
    for (int r = 0; r < 16; ++r) { accA[r] = bA; accB[r] = bB; }
    #pragma unroll 2
    for (int k = 0; k < K; k += 4) {
        float wa0 = W[(k + 0) * 128 + lane];
        float wa1 = W[(k + 1) * 128 + lane];
        float wa2 = W[(k + 2) * 128 + lane];
        float wa3 = W[(k + 3) * 128 + lane];
        float wb0 = W[(k + 0) * 128 + 64 + lane];
        float wb1 = W[(k + 1) * 128 + 64 + lane];
        float wb2 = W[(k + 2) * 128 + 64 + lane];
        float wb3 = W[(k + 3) * 128 + 64 + lane];
        #pragma unroll
        for (int r = 0; r < 16; ++r) {
            float4 x = *(const float4*)&xs_[(rbase + r) * LDX + k];
            accA[r] = fmaf(x.x, wa0, accA[r]);
            accA[r] = fmaf(x.y, wa1, accA[r]);
            accA[r] = fmaf(x.z, wa2, accA[r]);
            accA[r] = fmaf(x.w, wa3, accA[r]);
            accB[r] = fmaf(x.x, wb0, accB[r]);
            accB[r] = fmaf(x.y, wb1, accB[r]);
            accB[r] = fmaf(x.z, wb2, accB[r]);
            accB[r] = fmaf(x.w, wb3, accB[r]);
        }
    }
}

// ---------------- fused self branch: elu(feat@sW1+sb1)@sW2+sb2 ---------------
__global__ __launch_bounds__(256)
void k_self(const float* __restrict__ feat,
            const float* __restrict__ sW1, const float* __restrict__ sb1,
            const float* __restrict__ sW2, const float* __restrict__ sb2,
            float* __restrict__ outb) {
    __shared__ float xs[64 * 128];   // input [64][64] region, then h [64][128]
    const int t = threadIdx.x;
    const int row0 = blockIdx.x * 64;

    for (int idx = t; idx < 64 * 16; idx += 256) {
        int r = idx >> 4, c4 = idx & 15;
        int row = row0 + r;
        float4 v = make_float4(0.f, 0.f, 0.f, 0.f);
        if (row < N_NODES) v = *(const float4*)&feat[(size_t)row * 64 + c4 * 4];
        *(float4*)&xs[r * 64 + c4 * 4] = v;
    }
    __syncthreads();

    const int lane = t & 63, wv = t >> 6, rbase = wv * 16;
    float accA[16], accB[16];
    gemm_tile<64, 64>(xs, sW1, sb1, lane, rbase, accA, accB);
    __syncthreads();
    #pragma unroll
    for (int r = 0; r < 16; ++r) {
        xs[(rbase + r) * 128 + lane]      = elu_f(accA[r]);
        xs[(rbase + r) * 128 + 64 + lane] = elu_f(accB[r]);
    }
    __syncthreads();
    gemm_tile<128, 128>(xs, sW2, sb2, lane, rbase, accA, accB);

    #pragma unroll
    for (int r = 0; r < 16; ++r) {
        int row = row0 + rbase + r;
        if (row < N_NODES) {
            outb[(size_t)row * 128 + lane]      = accA[r];
            outb[(size_t)row * 128 + 64 + lane] = accB[r];
        }
    }
}

// ---------------- fused 4-layer MLP head over concat [agg | self] ------------
__global__ __launch_bounds__(256)
void k_head(const float* __restrict__ agg, const float* __restrict__ selfb,
            const float* __restrict__ mW1, const float* __restrict__ mb1,
            const float* __restrict__ mW2, const float* __restrict__ mb2,
            const float* __restrict__ mW3, const float* __restrict__ mb3,
            const float* __restrict__ mW4, const float* __restrict__ mb4,
            float* __restrict__ out) {
    __shared__ float xs[64 * 192];   // input [64][192], reused as h [64][128]
    const int t = threadIdx.x;
    const int row0 = blockIdx.x * 64;

    for (int idx = t; idx < 64 * 48; idx += 256) {
        int r = idx / 48, c4 = idx - r * 48;
        int row = row0 + r;
        float4 v = make_float4(0.f, 0.f, 0.f, 0.f);
        if (row < N_NODES) {
            if (c4 < 16) v = *(const float4*)&agg[(size_t)row * 64 + c4 * 4];
            else         v = *(const float4*)&selfb[(size_t)row * 128 + (c4 - 16) * 4];
        }
        *(float4*)&xs[r * 192 + c4 * 4] = v;
    }
    __syncthreads();

    const int lane = t & 63, wv = t >> 6, rbase = wv * 16;
    float accA[16], accB[16];

    gemm_tile<192, 192>(xs, mW1, mb1, lane, rbase, accA, accB);
    __syncthreads();
    #pragma unroll
    for (int r = 0; r < 16; ++r) {
        xs[(rbase + r) * 128 + lane]      = elu_f(accA[r]);
        xs[(rbase + r) * 128 + 64 + lane] = elu_f(accB[r]);
    }
    __syncthreads();

    gemm_tile<128, 128>(xs, mW2, mb2, lane, rbase, accA, accB);
    __syncthreads();
    #pragma unroll
    for (int r = 0; r < 16; ++r) {
        xs[(rbase + r) * 128 + lane]      = elu_f(accA[r]);
        xs[(rbase + r) * 128 + 64 + lane] = elu_f(accB[r]);
    }
    __syncthreads();

    gemm_tile<128, 128>(xs, mW3, mb3, lane, rbase, accA, accB);
    __syncthreads();
    #pragma unroll
    for (int r = 0; r < 16; ++r) {
        xs[(rbase + r) * 128 + lane]      = elu_f(accA[r]);
        xs[(rbase + r) * 128 + 64 + lane] = elu_f(accB[r]);
    }
    __syncthreads();

    gemm_tile<128, 128>(xs, mW4, mb4, lane, rbase, accA, accB);
    #pragma unroll
    for (int r = 0; r < 16; ++r) {
        int row = row0 + rbase + r;
        if (row < N_NODES) {
            out[(size_t)row * 128 + lane]      = accA[r];
            out[(size_t)row * 128 + 64 + lane] = accB[r];
        }
    }
}

// -----------------------------------------------------------------------------
extern "C" void kernel_launch(void* const* d_in, const int* in_sizes, int n_in,
                              void* d_out, int out_size, void* d_ws, size_t ws_size,
                              hipStream_t stream) {
    (void)in_sizes; (void)n_in; (void)out_size;
    const float* feat = (const float*)d_in[0];
    const float* off2 = (const float*)d_in[1];
    const int*   src  = (const int*)d_in[2];
    const int*   dst  = (const int*)d_in[3];
    const float* kW1  = (const float*)d_in[4];
    const float* kb1  = (const float*)d_in[5];
    const float* kW2  = (const float*)d_in[6];
    const float* kb2  = (const float*)d_in[7];
    const float* sW1  = (const float*)d_in[8];
    const float* sb1  = (const float*)d_in[9];
    const float* sW2  = (const float*)d_in[10];
    const float* sb2  = (const float*)d_in[11];
    const float* mW1  = (const float*)d_in[12];
    const float* mb1  = (const float*)d_in[13];
    const float* mW2  = (const float*)d_in[14];
    const float* mb2  = (const float*)d_in[15];
    const float* mW3  = (const float*)d_in[16];
    const float* mb3  = (const float*)d_in[17];
    const float* mW4  = (const float*)d_in[18];
    const float* mb4  = (const float*)d_in[19];

    char* ws = (char*)d_ws;
    size_t off = 0;
    auto alloc = [&](size_t bytes) -> void* {
        void* p = ws + off;
        off += (bytes + 255) & ~(size_t)255;
        return p;
    };
    int*   deg   = (int*)alloc((size_t)N_NODES * 4);
    int*   rs    = (int*)alloc((size_t)(N_NODES + 8) * 4);
    int*   cur   = (int*)alloc((size_t)N_NODES * 4);
    int*   eid   = (int*)alloc((size_t)N_EDGES * 4);
    float* agg   = (float*)alloc((size_t)N_NODES * 64 * 4);
    float* selfb = (float*)alloc((size_t)N_NODES * 128 * 4);
    const size_t kw_f32_bytes = (size_t)N_EDGES * 64 * 4;
    const bool kw_f32 = (ws_size - off) >= kw_f32_bytes;
    void* kwbuf = alloc(kw_f32 ? kw_f32_bytes : kw_f32_bytes / 2);

    hipMemsetAsync(deg, 0, (size_t)N_NODES * 4, stream);

    const int EB = (N_EDGES + 255) / 256;   // 3125
    const int KB = N_EDGES / 64;            // 12500
    const int GB = (N_NODES + 63) / 64;     // 782

    k_deg <<<EB, 256, 0, stream>>>(dst, deg);
    k_scan<<<1, 1024, 0, stream>>>(deg, rs, cur);
    k_fill<<<EB, 256, 0, stream>>>(dst, cur, eid);

    if (kw_f32) {
        k_kw<float> <<<KB, 256, 0, stream>>>(off2, kW1, kb1, kW2, kb2, (float*)kwbuf);
        k_agg<float><<<2048, 256, 0, stream>>>(off2, src, eid, rs, feat, (const float*)kwbuf, agg);
    } else {
        k_kw<__hip_bfloat16> <<<KB, 256, 0, stream>>>(off2, kW1, kb1, kW2, kb2, (__hip_bfloat16*)kwbuf);
        k_agg<__hip_bfloat16><<<2048, 256, 0, stream>>>(off2, src, eid, rs, feat,
                                                        (const __hip_bfloat16*)kwbuf, agg);
    }

    k_self<<<GB, 256, 0, stream>>>(feat, sW1, sb1, sW2, sb2, selfb);
    k_head<<<GB, 256, 0, stream>>>(agg, selfb, mW1, mb1, mW2, mb2, mW3, mb3, mW4, mb4,
                                   (float*)d_out);
}

// Round 4
// 765.102 us; speedup vs baseline: 1.5554x; 1.1197x over previous
//
#include <hip/hip_runtime.h>
#include <hip/hip_bf16.h>
#include <math.h>

#define N_NODES 50000
#define N_EDGES 800000
#define NB_SCAN ((N_NODES + 255) / 256)   // 196

__device__ __forceinline__ float elu_f(float x) { return x > 0.f ? x : expm1f(x); }
__device__ __forceinline__ float edge_score(float2 o) {
    return 1.f / (fabsf(o.x) + fabsf(o.y) + 0.001f);   // > 0 always
}

// ---------------- degree histogram ------------------------------------------
__global__ __launch_bounds__(256)
void k_deg(const int* __restrict__ dst, int* __restrict__ deg) {
    int e = blockIdx.x * 256 + threadIdx.x;
    if (e >= N_EDGES) return;
    atomicAdd(&deg[dst[e]], 1);
}

// ---------------- hierarchical scan: block sums ------------------------------
__global__ __launch_bounds__(256)
void k_bsum(const int* __restrict__ deg, int* __restrict__ bsum) {
    int i = blockIdx.x * 256 + threadIdx.x;
    int v = (i < N_NODES) ? deg[i] : 0;
    #pragma unroll
    for (int d = 32; d; d >>= 1) v += __shfl_xor(v, d);
    __shared__ int ws[4];
    if ((threadIdx.x & 63) == 0) ws[threadIdx.x >> 6] = v;
    __syncthreads();
    if (threadIdx.x == 0) bsum[blockIdx.x] = ws[0] + ws[1] + ws[2] + ws[3];
}

// ---------------- scan of the 196 block sums (1 block) -----------------------
__global__ __launch_bounds__(256)
void k_bscan(const int* __restrict__ bsum, int* __restrict__ bpre, int* __restrict__ rs) {
    const int t = threadIdx.x, lane = t & 63, wv = t >> 6;
    int v = (t < NB_SCAN) ? bsum[t] : 0;
    int inc = v;
    #pragma unroll
    for (int d = 1; d < 64; d <<= 1) { int u = __shfl_up(inc, d); if (lane >= d) inc += u; }
    __shared__ int wtot[4];
    if (lane == 63) wtot[wv] = inc;
    __syncthreads();
    int add = 0;
    for (int w = 0; w < wv; ++w) add += wtot[w];
    if (t < NB_SCAN) bpre[t] = inc + add - v;   // exclusive
    if (t == 0) rs[N_NODES] = N_EDGES;
}

// ---------------- write row-starts + cursor ----------------------------------
__global__ __launch_bounds__(256)
void k_wr(const int* __restrict__ deg, const int* __restrict__ bpre,
          int* __restrict__ rs, int* __restrict__ cur) {
    const int i = blockIdx.x * 256 + threadIdx.x;
    const int lane = threadIdx.x & 63, wv = threadIdx.x >> 6;
    int v = (i < N_NODES) ? deg[i] : 0;
    int inc = v;
    #pragma unroll
    for (int d = 1; d < 64; d <<= 1) { int u = __shfl_up(inc, d); if (lane >= d) inc += u; }
    __shared__ int wtot[4];
    if (lane == 63) wtot[wv] = inc;
    __syncthreads();
    int add = bpre[blockIdx.x];
    for (int w = 0; w < wv; ++w) add += wtot[w];
    if (i < N_NODES) { int excl = inc - v + add; rs[i] = excl; cur[i] = excl; }
}

// ---------------- CSR fill ---------------------------------------------------
__global__ __launch_bounds__(256)
void k_fill(const int* __restrict__ dst, int* __restrict__ cur, int* __restrict__ eid) {
    int e = blockIdx.x * 256 + threadIdx.x;
    if (e >= N_EDGES) return;
    int p = atomicAdd(&cur[dst[e]], 1);
    eid[p] = e;
}

// ---------------- per-edge kernel-weight GEMM --------------------------------
// 128 threads / 64 edges per block. Thread tile 4 edges x 8 cols:
// 32 FMA per (1 ds_read_b128 + 2 global float4). Hs 32 KB -> 5 blocks/CU.
template<typename KWT>
__global__ __launch_bounds__(128)
void k_kw(const float* __restrict__ off2,
          const float* __restrict__ kW1, const float* __restrict__ kb1,
          const float* __restrict__ kW2, const float* __restrict__ kb2,
          KWT* __restrict__ kwbuf) {
    __shared__ float Hs[128][64];
    const int t  = threadIdx.x;
    const int eb = blockIdx.x * 64;
    {
        const int le = t & 63, half = t >> 6;
        float2 o = ((const float2*)off2)[eb + le];
        #pragma unroll 8
        for (int ii = 0; ii < 64; ++ii) {
            int i = half * 64 + ii;
            float h = elu_f(fmaf(o.y, kW1[128 + i], fmaf(o.x, kW1[i], kb1[i])));
            Hs[i][le] = h;
        }
    }
    __syncthreads();

    const int e0 = (t >> 3) * 4;
    const int j0 = (t & 7) * 8;
    float c[4][8];
    #pragma unroll
    for (int a = 0; a < 4; ++a)
        #pragma unroll
        for (int b = 0; b < 8; ++b) c[a][b] = 0.f;

    #pragma unroll 4
    for (int i = 0; i < 128; ++i) {
        float4 hh = *(const float4*)&Hs[i][e0];
        float4 w0 = *(const float4*)&kW2[i * 64 + j0];
        float4 w1 = *(const float4*)&kW2[i * 64 + j0 + 4];
        const float ha[4] = {hh.x, hh.y, hh.z, hh.w};
        const float wb[8] = {w0.x, w0.y, w0.z, w0.w, w1.x, w1.y, w1.z, w1.w};
        #pragma unroll
        for (int a = 0; a < 4; ++a)
            #pragma unroll
            for (int b = 0; b < 8; ++b)
                c[a][b] = fmaf(ha[a], wb[b], c[a][b]);
    }

    float4 b0 = *(const float4*)&kb2[j0];
    float4 b1 = *(const float4*)&kb2[j0 + 4];
    const float bias8[8] = {b0.x, b0.y, b0.z, b0.w, b1.x, b1.y, b1.z, b1.w};
    #pragma unroll
    for (int a = 0; a < 4; ++a) {
        if constexpr (sizeof(KWT) == 4) {
            float* kp = (float*)kwbuf + (size_t)(eb + e0 + a) * 64 + j0;
            *(float4*)kp       = make_float4(c[a][0] + bias8[0], c[a][1] + bias8[1],
                                             c[a][2] + bias8[2], c[a][3] + bias8[3]);
            *(float4*)(kp + 4) = make_float4(c[a][4] + bias8[4], c[a][5] + bias8[5],
                                             c[a][6] + bias8[6], c[a][7] + bias8[7]);
        } else {
            __hip_bfloat16* kp = (__hip_bfloat16*)kwbuf + (size_t)(eb + e0 + a) * 64 + j0;
            #pragma unroll
            for (int b = 0; b < 8; ++b) kp[b] = __float2bfloat16(c[a][b] + bias8[b]);
        }
    }
}

// ---------------- per-node softmax + gather-aggregate ------------------------
// One wave per dst node; softmax recomputed in-wave (no atomics). Pass 3
// unrolled x4 with independent accumulators -> 4 concurrent load chains.
template<typename KWT>
__global__ __launch_bounds__(256)
void k_agg(const float* __restrict__ off2, const int* __restrict__ src,
           const int* __restrict__ eid, const int* __restrict__ rs,
           const float* __restrict__ feat, const KWT* __restrict__ kwbuf,
           float* __restrict__ agg) {
    const int lane = threadIdx.x & 63;
    const int wav  = threadIdx.x >> 6;
    const int gw   = blockIdx.x * 4 + wav;
    const int nw   = gridDim.x * 4;

    for (int n = gw; n < N_NODES; n += nw) {
        const int p0 = rs[n], p1 = rs[n + 1];
        if (p0 == p1) { agg[(size_t)n * 64 + lane] = 0.f; continue; }

        float mx = 0.f;
        for (int p = p0 + lane; p < p1; p += 64) {
            float2 o = ((const float2*)off2)[eid[p]];
            mx = fmaxf(mx, edge_score(o));
        }
        #pragma unroll
        for (int d = 32; d; d >>= 1) mx = fmaxf(mx, __shfl_xor(mx, d));

        float sm = 0.f;
        for (int p = p0 + lane; p < p1; p += 64) {
            float2 o = ((const float2*)off2)[eid[p]];
            sm += expf(edge_score(o) - mx);
        }
        #pragma unroll
        for (int d = 32; d; d >>= 1) sm += __shfl_xor(sm, d);
        const float dinv = 1.f / sm;

        float a0 = 0.f, a1 = 0.f, a2 = 0.f, a3 = 0.f;
        int p = p0;
        for (; p + 4 <= p1; p += 4) {
            const int e0 = eid[p], e1 = eid[p + 1], e2 = eid[p + 2], e3 = eid[p + 3];
            float2 o0 = ((const float2*)off2)[e0];
            float2 o1 = ((const float2*)off2)[e1];
            float2 o2 = ((const float2*)off2)[e2];
            float2 o3 = ((const float2*)off2)[e3];
            const int s0 = src[e0], s1 = src[e1], s2 = src[e2], s3 = src[e3];
            float f0 = feat[(size_t)s0 * 64 + lane];
            float f1 = feat[(size_t)s1 * 64 + lane];
            float f2 = feat[(size_t)s2 * 64 + lane];
            float f3 = feat[(size_t)s3 * 64 + lane];
            float k0, k1, k2, k3;
            if constexpr (sizeof(KWT) == 4) {
                k0 = ((const float*)kwbuf)[(size_t)e0 * 64 + lane];
                k1 = ((const float*)kwbuf)[(size_t)e1 * 64 + lane];
                k2 = ((const float*)kwbuf)[(size_t)e2 * 64 + lane];
                k3 = ((const float*)kwbuf)[(size_t)e3 * 64 + lane];
            } else {
                k0 = __bfloat162float(((const __hip_bfloat16*)kwbuf)[(size_t)e0 * 64 + lane]);
                k1 = __bfloat162float(((const __hip_bfloat16*)kwbuf)[(size_t)e1 * 64 + lane]);
                k2 = __bfloat162float(((const __hip_bfloat16*)kwbuf)[(size_t)e2 * 64 + lane]);
                k3 = __bfloat162float(((const __hip_bfloat16*)kwbuf)[(size_t)e3 * 64 + lane]);
            }
            float w0 = expf(edge_score(o0) - mx) * dinv;
            float w1 = expf(edge_score(o1) - mx) * dinv;
            float w2 = expf(edge_score(o2) - mx) * dinv;
            float w3 = expf(edge_score(o3) - mx) * dinv;
            a0 = fmaf(f0 * w0, k0, a0);
            a1 = fmaf(f1 * w1, k1, a1);
            a2 = fmaf(f2 * w2, k2, a2);
            a3 = fmaf(f3 * w3, k3, a3);
        }
        for (; p < p1; ++p) {
            const int e = eid[p];
            float2 o = ((const float2*)off2)[e];
            float wgt = expf(edge_score(o) - mx) * dinv;
            float f = feat[(size_t)src[e] * 64 + lane];
            float kv;
            if constexpr (sizeof(KWT) == 4) kv = ((const float*)kwbuf)[(size_t)e * 64 + lane];
            else kv = __bfloat162float(((const __hip_bfloat16*)kwbuf)[(size_t)e * 64 + lane]);
            a0 = fmaf(f * wgt, kv, a0);
        }
        agg[(size_t)n * 64 + lane] = (a0 + a1) + (a2 + a3);
    }
}

// ---------------- 64-row x 128-col GEMM tile from LDS ------------------------
template<int K, int LDX>
__device__ __forceinline__
void gemm_tile(const float* xs_, const float* __restrict__ W,
               const float* __restrict__ bias, int lane, int rbase,
               float accA[16], float accB[16]) {
    const float bA = bias[lane], bB = bias[lane + 64];
    #pragma unroll
    for (int r = 0; r < 16; ++r) { accA[r] = bA; accB[r] = bB; }
    #pragma unroll 2
    for (int k = 0; k < K; k += 4) {
        float wa0 = W[(k + 0) * 128 + lane];
        float wa1 = W[(k + 1) * 128 + lane];
        float wa2 = W[(k + 2) * 128 + lane];
        float wa3 = W[(k + 3) * 128 + lane];
        float wb0 = W[(k + 0) * 128 + 64 + lane];
        float wb1 = W[(k + 1) * 128 + 64 + lane];
        float wb2 = W[(k + 2) * 128 + 64 + lane];
        float wb3 = W[(k + 3) * 128 + 64 + lane];
        #pragma unroll
        for (int r = 0; r < 16; ++r) {
            float4 x = *(const float4*)&xs_[(rbase + r) * LDX + k];
            accA[r] = fmaf(x.x, wa0, accA[r]);
            accA[r] = fmaf(x.y, wa1, accA[r]);
            accA[r] = fmaf(x.z, wa2, accA[r]);
            accA[r] = fmaf(x.w, wa3, accA[r]);
            accB[r] = fmaf(x.x, wb0, accB[r]);
            accB[r] = fmaf(x.y, wb1, accB[r]);
            accB[r] = fmaf(x.z, wb2, accB[r]);
            accB[r] = fmaf(x.w, wb3, accB[r]);
        }
    }
}

// ---------------- fused self branch ------------------------------------------
__global__ __launch_bounds__(256)
void k_self(const float* __restrict__ feat,
            const float* __restrict__ sW1, const float* __restrict__ sb1,
            const float* __restrict__ sW2, const float* __restrict__ sb2,
            float* __restrict__ outb) {
    __shared__ float xs[64 * 128];
    const int t = threadIdx.x;
    const int row0 = blockIdx.x * 64;

    for (int idx = t; idx < 64 * 16; idx += 256) {
        int r = idx >> 4, c4 = idx & 15;
        int row = row0 + r;
        float4 v = make_float4(0.f, 0.f, 0.f, 0.f);
        if (row < N_NODES) v = *(const float4*)&feat[(size_t)row * 64 + c4 * 4];
        *(float4*)&xs[r * 64 + c4 * 4] = v;
    }
    __syncthreads();

    const int lane = t & 63, wv = t >> 6, rbase = wv * 16;
    float accA[16], accB[16];
    gemm_tile<64, 64>(xs, sW1, sb1, lane, rbase, accA, accB);
    __syncthreads();
    #pragma unroll
    for (int r = 0; r < 16; ++r) {
        xs[(rbase + r) * 128 + lane]      = elu_f(accA[r]);
        xs[(rbase + r) * 128 + 64 + lane] = elu_f(accB[r]);
    }
    __syncthreads();
    gemm_tile<128, 128>(xs, sW2, sb2, lane, rbase, accA, accB);

    #pragma unroll
    for (int r = 0; r < 16; ++r) {
        int row = row0 + rbase + r;
        if (row < N_NODES) {
            outb[(size_t)row * 128 + lane]      = accA[r];
            outb[(size_t)row * 128 + 64 + lane] = accB[r];
        }
    }
}

// ---------------- fused 4-layer MLP head -------------------------------------
__global__ __launch_bounds__(256)
void k_head(const float* __restrict__ agg, const float* __restrict__ selfb,
            const float* __restrict__ mW1, const float* __restrict__ mb1,
            const float* __restrict__ mW2, const float* __restrict__ mb2,
            const float* __restrict__ mW3, const float* __restrict__ mb3,
            const float* __restrict__ mW4, const float* __restrict__ mb4,
            float* __restrict__ out) {
    __shared__ float xs[64 * 192];
    const int t = threadIdx.x;
    const int row0 = blockIdx.x * 64;

    for (int idx = t; idx < 64 * 48; idx += 256) {
        int r = idx / 48, c4 = idx - r * 48;
        int row = row0 + r;
        float4 v = make_float4(0.f, 0.f, 0.f, 0.f);
        if (row < N_NODES) {
            if (c4 < 16) v = *(const float4*)&agg[(size_t)row * 64 + c4 * 4];
            else         v = *(const float4*)&selfb[(size_t)row * 128 + (c4 - 16) * 4];
        }
        *(float4*)&xs[r * 192 + c4 * 4] = v;
    }
    __syncthreads();

    const int lane = t & 63, wv = t >> 6, rbase = wv * 16;
    float accA[16], accB[16];

    gemm_tile<192, 192>(xs, mW1, mb1, lane, rbase, accA, accB);
    __syncthreads();
    #pragma unroll
    for (int r = 0; r < 16; ++r) {
        xs[(rbase + r) * 128 + lane]      = elu_f(accA[r]);
        xs[(rbase + r) * 128 + 64 + lane] = elu_f(accB[r]);
    }
    __syncthreads();

    gemm_tile<128, 128>(xs, mW2, mb2, lane, rbase, accA, accB);
    __syncthreads();
    #pragma unroll
    for (int r = 0; r < 16; ++r) {
        xs[(rbase + r) * 128 + lane]      = elu_f(accA[r]);
        xs[(rbase + r) * 128 + 64 + lane] = elu_f(accB[r]);
    }
    __syncthreads();

    gemm_tile<128, 128>(xs, mW3, mb3, lane, rbase, accA, accB);
    __syncthreads();
    #pragma unroll
    for (int r = 0; r < 16; ++r) {
        xs[(rbase + r) * 128 + lane]      = elu_f(accA[r]);
        xs[(rbase + r) * 128 + 64 + lane] = elu_f(accB[r]);
    }
    __syncthreads();

    gemm_tile<128, 128>(xs, mW4, mb4, lane, rbase, accA, accB);
    #pragma unroll
    for (int r = 0; r < 16; ++r) {
        int row = row0 + rbase + r;
        if (row < N_NODES) {
            out[(size_t)row * 128 + lane]      = accA[r];
            out[(size_t)row * 128 + 64 + lane] = accB[r];
        }
    }
}

// -----------------------------------------------------------------------------
extern "C" void kernel_launch(void* const* d_in, const int* in_sizes, int n_in,
                              void* d_out, int out_size, void* d_ws, size_t ws_size,
                              hipStream_t stream) {
    (void)in_sizes; (void)n_in; (void)out_size;
    const float* feat = (const float*)d_in[0];
    const float* off2 = (const float*)d_in[1];
    const int*   src  = (const int*)d_in[2];
    const int*   dst  = (const int*)d_in[3];
    const float* kW1  = (const float*)d_in[4];
    const float* kb1  = (const float*)d_in[5];
    const float* kW2  = (const float*)d_in[6];
    const float* kb2  = (const float*)d_in[7];
    const float* sW1  = (const float*)d_in[8];
    const float* sb1  = (const float*)d_in[9];
    const float* sW2  = (const float*)d_in[10];
    const float* sb2  = (const float*)d_in[11];
    const float* mW1  = (const float*)d_in[12];
    const float* mb1  = (const float*)d_in[13];
    const float* mW2  = (const float*)d_in[14];
    const float* mb2  = (const float*)d_in[15];
    const float* mW3  = (const float*)d_in[16];
    const float* mb3  = (const float*)d_in[17];
    const float* mW4  = (const float*)d_in[18];
    const float* mb4  = (const float*)d_in[19];

    char* ws = (char*)d_ws;
    size_t off = 0;
    auto alloc = [&](size_t bytes) -> void* {
        void* p = ws + off;
        off += (bytes + 255) & ~(size_t)255;
        return p;
    };
    int*   deg   = (int*)alloc((size_t)N_NODES * 4);
    int*   rs    = (int*)alloc((size_t)(N_NODES + 8) * 4);
    int*   cur   = (int*)alloc((size_t)N_NODES * 4);
    int*   bsum  = (int*)alloc((size_t)NB_SCAN * 4);
    int*   bpre  = (int*)alloc((size_t)NB_SCAN * 4);
    int*   eid   = (int*)alloc((size_t)N_EDGES * 4);
    float* agg   = (float*)alloc((size_t)N_NODES * 64 * 4);
    float* selfb = (float*)alloc((size_t)N_NODES * 128 * 4);
    const size_t kw_f32_bytes = (size_t)N_EDGES * 64 * 4;
    const bool kw_f32 = (ws_size - off) >= kw_f32_bytes;
    void* kwbuf = alloc(kw_f32 ? kw_f32_bytes : kw_f32_bytes / 2);

    hipMemsetAsync(deg, 0, (size_t)N_NODES * 4, stream);

    const int EB = (N_EDGES + 255) / 256;   // 3125
    const int KB = N_EDGES / 64;            // 12500
    const int GB = (N_NODES + 63) / 64;     // 782

    k_deg  <<<EB, 256, 0, stream>>>(dst, deg);
    k_bsum <<<NB_SCAN, 256, 0, stream>>>(deg, bsum);
    k_bscan<<<1, 256, 0, stream>>>(bsum, bpre, rs);
    k_wr   <<<NB_SCAN, 256, 0, stream>>>(deg, bpre, rs, cur);
    k_fill <<<EB, 256, 0, stream>>>(dst, cur, eid);

    if (kw_f32) {
        k_kw<float> <<<KB, 128, 0, stream>>>(off2, kW1, kb1, kW2, kb2, (float*)kwbuf);
        k_agg<float><<<2048, 256, 0, stream>>>(off2, src, eid, rs, feat, (const float*)kwbuf, agg);
    } else {
        k_kw<__hip_bfloat16> <<<KB, 128, 0, stream>>>(off2, kW1, kb1, kW2, kb2, (__hip_bfloat16*)kwbuf);
        k_agg<__hip_bfloat16><<<2048, 256, 0, stream>>>(off2, src, eid, rs, feat,
                                                        (const __hip_bfloat16*)kwbuf, agg);
    }

    k_self<<<GB, 256, 0, stream>>>(feat, sW1, sb1, sW2, sb2, selfb);
    k_head<<<GB, 256, 0, stream>>>(agg, selfb, mW1, mb1, mW2, mb2, mW3, mb3, mW4, mb4,
                                   (float*)d_out);
}

// Round 5
// 577.024 us; speedup vs baseline: 2.0623x; 1.3259x over previous
//
#include <hip/hip_runtime.h>
#include <hip/hip_bf16.h>
#include <math.h>

#define N_NODES 50000
#define N_EDGES 800000
#define NB_SCAN ((N_NODES + 255) / 256)   // 196

typedef _Float16 half8 __attribute__((ext_vector_type(8)));
typedef float f32x4 __attribute__((ext_vector_type(4)));

__device__ __forceinline__ float elu_f(float x) { return x > 0.f ? x : expm1f(x); }
__device__ __forceinline__ float edge_score(float2 o) {
    return 1.f / (fabsf(o.x) + fabsf(o.y) + 0.001f);   // > 0 always
}

// ---------------- degree histogram ------------------------------------------
__global__ __launch_bounds__(256)
void k_deg(const int* __restrict__ dst, int* __restrict__ deg) {
    int e = blockIdx.x * 256 + threadIdx.x;
    if (e >= N_EDGES) return;
    atomicAdd(&deg[dst[e]], 1);
}

// ---------------- hierarchical scan: block sums ------------------------------
__global__ __launch_bounds__(256)
void k_bsum(const int* __restrict__ deg, int* __restrict__ bsum) {
    int i = blockIdx.x * 256 + threadIdx.x;
    int v = (i < N_NODES) ? deg[i] : 0;
    #pragma unroll
    for (int d = 32; d; d >>= 1) v += __shfl_xor(v, d);
    __shared__ int ws[4];
    if ((threadIdx.x & 63) == 0) ws[threadIdx.x >> 6] = v;
    __syncthreads();
    if (threadIdx.x == 0) bsum[blockIdx.x] = ws[0] + ws[1] + ws[2] + ws[3];
}

// ---------------- scan of the 196 block sums (1 block) -----------------------
__global__ __launch_bounds__(256)
void k_bscan(const int* __restrict__ bsum, int* __restrict__ bpre, int* __restrict__ rs) {
    const int t = threadIdx.x, lane = t & 63, wv = t >> 6;
    int v = (t < NB_SCAN) ? bsum[t] : 0;
    int inc = v;
    #pragma unroll
    for (int d = 1; d < 64; d <<= 1) { int u = __shfl_up(inc, d); if (lane >= d) inc += u; }
    __shared__ int wtot[4];
    if (lane == 63) wtot[wv] = inc;
    __syncthreads();
    int add = 0;
    for (int w = 0; w < wv; ++w) add += wtot[w];
    if (t < NB_SCAN) bpre[t] = inc + add - v;   // exclusive
    if (t == 0) rs[N_NODES] = N_EDGES;
}

// ---------------- write row-starts + cursor ----------------------------------
__global__ __launch_bounds__(256)
void k_wr(const int* __restrict__ deg, const int* __restrict__ bpre,
          int* __restrict__ rs, int* __restrict__ cur) {
    const int i = blockIdx.x * 256 + threadIdx.x;
    const int lane = threadIdx.x & 63, wv = threadIdx.x >> 6;
    int v = (i < N_NODES) ? deg[i] : 0;
    int inc = v;
    #pragma unroll
    for (int d = 1; d < 64; d <<= 1) { int u = __shfl_up(inc, d); if (lane >= d) inc += u; }
    __shared__ int wtot[4];
    if (lane == 63) wtot[wv] = inc;
    __syncthreads();
    int add = bpre[blockIdx.x];
    for (int w = 0; w < wv; ++w) add += wtot[w];
    if (i < N_NODES) { int excl = inc - v + add; rs[i] = excl; cur[i] = excl; }
}

// ---------------- CSR fill ---------------------------------------------------
__global__ __launch_bounds__(256)
void k_fill(const int* __restrict__ dst, int* __restrict__ cur, int* __restrict__ eid) {
    int e = blockIdx.x * 256 + threadIdx.x;
    if (e >= N_EDGES) return;
    int p = atomicAdd(&cur[dst[e]], 1);
    eid[p] = e;
}

// ---------------- per-edge kernel-weight GEMM via f16 hi/lo split MFMA -------
// Block = 256 thr (4 waves), 64 edges. H[64][128] -> LDS as f16 hi+lo,
// XOR-swizzled (G4). Wave w owns col-tile w (16 cols): B-frags (kW2) in regs,
// 4 m-tiles x 4 k-steps x 3 split-terms = 48 mfma_f32_16x16x32_f16 per wave.
// Result is fp32-accurate (dropped lo*lo term ~2^-22 relative).
template<typename KWT>
__global__ __launch_bounds__(256)
void k_kw(const float* __restrict__ off2,
          const float* __restrict__ kW1, const float* __restrict__ kb1,
          const float* __restrict__ kW2, const float* __restrict__ kb2,
          KWT* __restrict__ kwbuf) {
    __shared__ _Float16 HsH[64 * 128];   // 16 KB
    __shared__ _Float16 HsL[64 * 128];   // 16 KB
    const int t  = threadIdx.x;
    const int eb = blockIdx.x * 64;

    // Phase 1: H hi/lo -> LDS. Thread t: edge t&63, k-range (t>>6)*32..+31.
    {
        const int e  = t & 63;
        const int kq = (t >> 6) * 32;
        float2 o = ((const float2*)off2)[eb + e];
        #pragma unroll
        for (int kk = 0; kk < 32; kk += 8) {
            half8 vh, vl;
            #pragma unroll
            for (int i = 0; i < 8; ++i) {
                int k = kq + kk + i;
                float h = elu_f(fmaf(o.y, kW1[128 + k], fmaf(o.x, kW1[k], kb1[k])));
                _Float16 hh = (_Float16)h;
                vh[i] = hh;
                vl[i] = (_Float16)(h - (float)hh);
            }
            int byte = ((e * 128 + kq + kk) * 2) ^ ((e & 7) << 4);
            *(half8*)((char*)HsH + byte) = vh;
            *(half8*)((char*)HsL + byte) = vl;
        }
    }
    __syncthreads();

    // Phase 2: MFMA. Wave wv = col-tile; lane: colg = lane&15, lq = lane>>4.
    const int lane = t & 63;
    const int wv   = t >> 6;
    const int colg = lane & 15;
    const int lq   = lane >> 4;

    half8 Bh[4], Bl[4];
    #pragma unroll
    for (int kt = 0; kt < 4; ++kt) {
        #pragma unroll
        for (int i = 0; i < 8; ++i) {
            int k = kt * 32 + lq * 8 + i;
            float w = kW2[k * 64 + wv * 16 + colg];
            _Float16 wh = (_Float16)w;
            Bh[kt][i] = wh;
            Bl[kt][i] = (_Float16)(w - (float)wh);
        }
    }
    const float b2 = kb2[wv * 16 + colg];

    #pragma unroll
    for (int m = 0; m < 4; ++m) {
        f32x4 c = {0.f, 0.f, 0.f, 0.f};
        const int row = m * 16 + colg;
        #pragma unroll
        for (int kt = 0; kt < 4; ++kt) {
            int byte = ((row * 128 + kt * 32 + lq * 8) * 2) ^ ((row & 7) << 4);
            half8 Ah = *(const half8*)((const char*)HsH + byte);
            half8 Al = *(const half8*)((const char*)HsL + byte);
            c = __builtin_amdgcn_mfma_f32_16x16x32_f16(Ah, Bh[kt], c, 0, 0, 0);
            c = __builtin_amdgcn_mfma_f32_16x16x32_f16(Ah, Bl[kt], c, 0, 0, 0);
            c = __builtin_amdgcn_mfma_f32_16x16x32_f16(Al, Bh[kt], c, 0, 0, 0);
        }
        // D layout: col = lane&15, row = (lane>>4)*4 + r  (m89-verified)
        #pragma unroll
        for (int r = 0; r < 4; ++r) {
            int e = eb + m * 16 + lq * 4 + r;
            float v = c[r] + b2;
            if constexpr (sizeof(KWT) == 4)
                ((float*)kwbuf)[(size_t)e * 64 + wv * 16 + colg] = v;
            else
                ((__hip_bfloat16*)kwbuf)[(size_t)e * 64 + wv * 16 + colg] = __float2bfloat16(v);
        }
    }
}

// ---------------- per-node softmax + gather-aggregate ------------------------
template<typename KWT>
__global__ __launch_bounds__(256)
void k_agg(const float* __restrict__ off2, const int* __restrict__ src,
           const int* __restrict__ eid, const int* __restrict__ rs,
           const float* __restrict__ feat, const KWT* __restrict__ kwbuf,
           float* __restrict__ agg) {
    const int lane = threadIdx.x & 63;
    const int wav  = threadIdx.x >> 6;
    const int gw   = blockIdx.x * 4 + wav;
    const int nw   = gridDim.x * 4;

    for (int n = gw; n < N_NODES; n += nw) {
        const int p0 = rs[n], p1 = rs[n + 1];
        if (p0 == p1) { agg[(size_t)n * 64 + lane] = 0.f; continue; }

        float mx = 0.f;
        for (int p = p0 + lane; p < p1; p += 64) {
            float2 o = ((const float2*)off2)[eid[p]];
            mx = fmaxf(mx, edge_score(o));
        }
        #pragma unroll
        for (int d = 32; d; d >>= 1) mx = fmaxf(mx, __shfl_xor(mx, d));

        float sm = 0.f;
        for (int p = p0 + lane; p < p1; p += 64) {
            float2 o = ((const float2*)off2)[eid[p]];
            sm += expf(edge_score(o) - mx);
        }
        #pragma unroll
        for (int d = 32; d; d >>= 1) sm += __shfl_xor(sm, d);
        const float dinv = 1.f / sm;

        float a0 = 0.f, a1 = 0.f, a2 = 0.f, a3 = 0.f;
        int p = p0;
        for (; p + 4 <= p1; p += 4) {
            const int e0 = eid[p], e1 = eid[p + 1], e2 = eid[p + 2], e3 = eid[p + 3];
            float2 o0 = ((const float2*)off2)[e0];
            float2 o1 = ((const float2*)off2)[e1];
            float2 o2 = ((const float2*)off2)[e2];
            float2 o3 = ((const float2*)off2)[e3];
            const int s0 = src[e0], s1 = src[e1], s2 = src[e2], s3 = src[e3];
            float f0 = feat[(size_t)s0 * 64 + lane];
            float f1 = feat[(size_t)s1 * 64 + lane];
            float f2 = feat[(size_t)s2 * 64 + lane];
            float f3 = feat[(size_t)s3 * 64 + lane];
            float k0, k1, k2, k3;
            if constexpr (sizeof(KWT) == 4) {
                k0 = ((const float*)kwbuf)[(size_t)e0 * 64 + lane];
                k1 = ((const float*)kwbuf)[(size_t)e1 * 64 + lane];
                k2 = ((const float*)kwbuf)[(size_t)e2 * 64 + lane];
                k3 = ((const float*)kwbuf)[(size_t)e3 * 64 + lane];
            } else {
                k0 = __bfloat162float(((const __hip_bfloat16*)kwbuf)[(size_t)e0 * 64 + lane]);
                k1 = __bfloat162float(((const __hip_bfloat16*)kwbuf)[(size_t)e1 * 64 + lane]);
                k2 = __bfloat162float(((const __hip_bfloat16*)kwbuf)[(size_t)e2 * 64 + lane]);
                k3 = __bfloat162float(((const __hip_bfloat16*)kwbuf)[(size_t)e3 * 64 + lane]);
            }
            float w0 = expf(edge_score(o0) - mx) * dinv;
            float w1 = expf(edge_score(o1) - mx) * dinv;
            float w2 = expf(edge_score(o2) - mx) * dinv;
            float w3 = expf(edge_score(o3) - mx) * dinv;
            a0 = fmaf(f0 * w0, k0, a0);
            a1 = fmaf(f1 * w1, k1, a1);
            a2 = fmaf(f2 * w2, k2, a2);
            a3 = fmaf(f3 * w3, k3, a3);
        }
        for (; p < p1; ++p) {
            const int e = eid[p];
            float2 o = ((const float2*)off2)[e];
            float wgt = expf(edge_score(o) - mx) * dinv;
            float f = feat[(size_t)src[e] * 64 + lane];
            float kv;
            if constexpr (sizeof(KWT) == 4) kv = ((const float*)kwbuf)[(size_t)e * 64 + lane];
            else kv = __bfloat162float(((const __hip_bfloat16*)kwbuf)[(size_t)e * 64 + lane]);
            a0 = fmaf(f * wgt, kv, a0);
        }
        agg[(size_t)n * 64 + lane] = (a0 + a1) + (a2 + a3);
    }
}

// ---------------- 64-row x 128-col GEMM tile from LDS ------------------------
template<int K, int LDX>
__device__ __forceinline__
void gemm_tile(const float* xs_, const float* __restrict__ W,
               const float* __restrict__ bias, int lane, int rbase,
               float accA[16], float accB[16]) {
    const float bA = bias[lane], bB = bias[lane + 64];
    #pragma unroll
    for (int r = 0; r < 16; ++r) { accA[r] = bA; accB[r] = bB; }
    #pragma unroll 2
    for (int k = 0; k < K; k += 4) {
        float wa0 = W[(k + 0) * 128 + lane];
        float wa1 = W[(k + 1) * 128 + lane];
        float wa2 = W[(k + 2) * 128 + lane];
        float wa3 = W[(k + 3) * 128 + lane];
        float wb0 = W[(k + 0) * 128 + 64 + lane];
        float wb1 = W[(k + 1) * 128 + 64 + lane];
        float wb2 = W[(k + 2) * 128 + 64 + lane];
        float wb3 = W[(k + 3) * 128 + 64 + lane];
        #pragma unroll
        for (int r = 0; r < 16; ++r) {
            float4 x = *(const float4*)&xs_[(rbase + r) * LDX + k];
            accA[r] = fmaf(x.x, wa0, accA[r]);
            accA[r] = fmaf(x.y, wa1, accA[r]);
            accA[r] = fmaf(x.z, wa2, accA[r]);
            accA[r] = fmaf(x.w, wa3, accA[r]);
            accB[r] = fmaf(x.x, wb0, accB[r]);
            accB[r] = fmaf(x.y, wb1, accB[r]);
            accB[r] = fmaf(x.z, wb2, accB[r]);
            accB[r] = fmaf(x.w, wb3, accB[r]);
        }
    }
}

// ---------------- fused self branch ------------------------------------------
__global__ __launch_bounds__(256)
void k_self(const float* __restrict__ feat,
            const float* __restrict__ sW1, const float* __restrict__ sb1,
            const float* __restrict__ sW2, const float* __restrict__ sb2,
            float* __restrict__ outb) {
    __shared__ float xs[64 * 128];
    const int t = threadIdx.x;
    const int row0 = blockIdx.x * 64;

    for (int idx = t; idx < 64 * 16; idx += 256) {
        int r = idx >> 4, c4 = idx & 15;
        int row = row0 + r;
        float4 v = make_float4(0.f, 0.f, 0.f, 0.f);
        if (row < N_NODES) v = *(const float4*)&feat[(size_t)row * 64 + c4 * 4];
        *(float4*)&xs[r * 64 + c4 * 4] = v;
    }
    __syncthreads();

    const int lane = t & 63, wv = t >> 6, rbase = wv * 16;
    float accA[16], accB[16];
    gemm_tile<64, 64>(xs, sW1, sb1, lane, rbase, accA, accB);
    __syncthreads();
    #pragma unroll
    for (int r = 0; r < 16; ++r) {
        xs[(rbase + r) * 128 + lane]      = elu_f(accA[r]);
        xs[(rbase + r) * 128 + 64 + lane] = elu_f(accB[r]);
    }
    __syncthreads();
    gemm_tile<128, 128>(xs, sW2, sb2, lane, rbase, accA, accB);

    #pragma unroll
    for (int r = 0; r < 16; ++r) {
        int row = row0 + rbase + r;
        if (row < N_NODES) {
            outb[(size_t)row * 128 + lane]      = accA[r];
            outb[(size_t)row * 128 + 64 + lane] = accB[r];
        }
    }
}

// ---------------- fused 4-layer MLP head -------------------------------------
__global__ __launch_bounds__(256)
void k_head(const float* __restrict__ agg, const float* __restrict__ selfb,
            const float* __restrict__ mW1, const float* __restrict__ mb1,
            const float* __restrict__ mW2, const float* __restrict__ mb2,
            const float* __restrict__ mW3, const float* __restrict__ mb3,
            const float* __restrict__ mW4, const float* __restrict__ mb4,
            float* __restrict__ out) {
    __shared__ float xs[64 * 192];
    const int t = threadIdx.x;
    const int row0 = blockIdx.x * 64;

    for (int idx = t; idx < 64 * 48; idx += 256) {
        int r = idx / 48, c4 = idx - r * 48;
        int row = row0 + r;
        float4 v = make_float4(0.f, 0.f, 0.f, 0.f);
        if (row < N_NODES) {
            if (c4 < 16) v = *(const float4*)&agg[(size_t)row * 64 + c4 * 4];
            else         v = *(const float4*)&selfb[(size_t)row * 128 + (c4 - 16) * 4];
        }
        *(float4*)&xs[r * 192 + c4 * 4] = v;
    }
    __syncthreads();

    const int lane = t & 63, wv = t >> 6, rbase = wv * 16;
    float accA[16], accB[16];

    gemm_tile<192, 192>(xs, mW1, mb1, lane, rbase, accA, accB);
    __syncthreads();
    #pragma unroll
    for (int r = 0; r < 16; ++r) {
        xs[(rbase + r) * 128 + lane]      = elu_f(accA[r]);
        xs[(rbase + r) * 128 + 64 + lane] = elu_f(accB[r]);
    }
    __syncthreads();

    gemm_tile<128, 128>(xs, mW2, mb2, lane, rbase, accA, accB);
    __syncthreads();
    #pragma unroll
    for (int r = 0; r < 16; ++r) {
        xs[(rbase + r) * 128 + lane]      = elu_f(accA[r]);
        xs[(rbase + r) * 128 + 64 + lane] = elu_f(accB[r]);
    }
    __syncthreads();

    gemm_tile<128, 128>(xs, mW3, mb3, lane, rbase, accA, accB);
    __syncthreads();
    #pragma unroll
    for (int r = 0; r < 16; ++r) {
        xs[(rbase + r) * 128 + lane]      = elu_f(accA[r]);
        xs[(rbase + r) * 128 + 64 + lane] = elu_f(accB[r]);
    }
    __syncthreads();

    gemm_tile<128, 128>(xs, mW4, mb4, lane, rbase, accA, accB);
    #pragma unroll
    for (int r = 0; r < 16; ++r) {
        int row = row0 + rbase + r;
        if (row < N_NODES) {
            out[(size_t)row * 128 + lane]      = accA[r];
            out[(size_t)row * 128 + 64 + lane] = accB[r];
        }
    }
}

// -----------------------------------------------------------------------------
extern "C" void kernel_launch(void* const* d_in, const int* in_sizes, int n_in,
                              void* d_out, int out_size, void* d_ws, size_t ws_size,
                              hipStream_t stream) {
    (void)in_sizes; (void)n_in; (void)out_size;
    const float* feat = (const float*)d_in[0];
    const float* off2 = (const float*)d_in[1];
    const int*   src  = (const int*)d_in[2];
    const int*   dst  = (const int*)d_in[3];
    const float* kW1  = (const float*)d_in[4];
    const float* kb1  = (const float*)d_in[5];
    const float* kW2  = (const float*)d_in[6];
    const float* kb2  = (const float*)d_in[7];
    const float* sW1  = (const float*)d_in[8];
    const float* sb1  = (const float*)d_in[9];
    const float* sW2  = (const float*)d_in[10];
    const float* sb2  = (const float*)d_in[11];
    const float* mW1  = (const float*)d_in[12];
    const float* mb1  = (const float*)d_in[13];
    const float* mW2  = (const float*)d_in[14];
    const float* mb2  = (const float*)d_in[15];
    const float* mW3  = (const float*)d_in[16];
    const float* mb3  = (const float*)d_in[17];
    const float* mW4  = (const float*)d_in[18];
    const float* mb4  = (const float*)d_in[19];

    char* ws = (char*)d_ws;
    size_t off = 0;
    auto alloc = [&](size_t bytes) -> void* {
        void* p = ws + off;
        off += (bytes + 255) & ~(size_t)255;
        return p;
    };
    int*   deg   = (int*)alloc((size_t)N_NODES * 4);
    int*   rs    = (int*)alloc((size_t)(N_NODES + 8) * 4);
    int*   cur   = (int*)alloc((size_t)N_NODES * 4);
    int*   bsum  = (int*)alloc((size_t)NB_SCAN * 4);
    int*   bpre  = (int*)alloc((size_t)NB_SCAN * 4);
    int*   eid   = (int*)alloc((size_t)N_EDGES * 4);
    float* agg   = (float*)alloc((size_t)N_NODES * 64 * 4);
    float* selfb = (float*)alloc((size_t)N_NODES * 128 * 4);
    const size_t kw_f32_bytes = (size_t)N_EDGES * 64 * 4;
    const bool kw_f32 = (ws_size - off) >= kw_f32_bytes;
    void* kwbuf = alloc(kw_f32 ? kw_f32_bytes : kw_f32_bytes / 2);

    hipMemsetAsync(deg, 0, (size_t)N_NODES * 4, stream);

    const int EB = (N_EDGES + 255) / 256;   // 3125
    const int KB = N_EDGES / 64;            // 12500
    const int GB = (N_NODES + 63) / 64;     // 782

    k_deg  <<<EB, 256, 0, stream>>>(dst, deg);
    k_bsum <<<NB_SCAN, 256, 0, stream>>>(deg, bsum);
    k_bscan<<<1, 256, 0, stream>>>(bsum, bpre, rs);
    k_wr   <<<NB_SCAN, 256, 0, stream>>>(deg, bpre, rs, cur);
    k_fill <<<EB, 256, 0, stream>>>(dst, cur, eid);

    if (kw_f32) {
        k_kw<float> <<<KB, 256, 0, stream>>>(off2, kW1, kb1, kW2, kb2, (float*)kwbuf);
        k_agg<float><<<2048, 256, 0, stream>>>(off2, src, eid, rs, feat, (const float*)kwbuf, agg);
    } else {
        k_kw<__hip_bfloat16> <<<KB, 256, 0, stream>>>(off2, kW1, kb1, kW2, kb2, (__hip_bfloat16*)kwbuf);
        k_agg<__hip_bfloat16><<<2048, 256, 0, stream>>>(off2, src, eid, rs, feat,
                                                        (const __hip_bfloat16*)kwbuf, agg);
    }

    k_self<<<GB, 256, 0, stream>>>(feat, sW1, sb1, sW2, sb2, selfb);
    k_head<<<GB, 256, 0, stream>>>(agg, selfb, mW1, mb1, mW2, mb2, mW3, mb3, mW4, mb4,
                                   (float*)d_out);
}

// Round 6
// 385.168 us; speedup vs baseline: 3.0896x; 1.4981x over previous
//
#include <hip/hip_runtime.h>
#include <hip/hip_bf16.h>
#include <math.h>

#define N_NODES 50000
#define N_EDGES 800000
#define NB_SCAN ((N_NODES + 255) / 256)   // 196

typedef _Float16 half8 __attribute__((ext_vector_type(8)));
typedef float f32x4 __attribute__((ext_vector_type(4)));

__device__ __forceinline__ float elu_f(float x) { return x > 0.f ? x : expm1f(x); }
__device__ __forceinline__ float edge_score(float2 o) {
    return 1.f / (fabsf(o.x) + fabsf(o.y) + 0.001f);   // > 0 always
}

// ======================= CSR build =========================================
__global__ __launch_bounds__(256)
void k_deg(const int* __restrict__ dst, int* __restrict__ deg) {
    int e = blockIdx.x * 256 + threadIdx.x;
    if (e >= N_EDGES) return;
    atomicAdd(&deg[dst[e]], 1);
}

__global__ __launch_bounds__(256)
void k_bsum(const int* __restrict__ deg, int* __restrict__ bsum) {
    int i = blockIdx.x * 256 + threadIdx.x;
    int v = (i < N_NODES) ? deg[i] : 0;
    #pragma unroll
    for (int d = 32; d; d >>= 1) v += __shfl_xor(v, d);
    __shared__ int ws[4];
    if ((threadIdx.x & 63) == 0) ws[threadIdx.x >> 6] = v;
    __syncthreads();
    if (threadIdx.x == 0) bsum[blockIdx.x] = ws[0] + ws[1] + ws[2] + ws[3];
}

__global__ __launch_bounds__(256)
void k_bscan(const int* __restrict__ bsum, int* __restrict__ bpre, int* __restrict__ rs) {
    const int t = threadIdx.x, lane = t & 63, wv = t >> 6;
    int v = (t < NB_SCAN) ? bsum[t] : 0;
    int inc = v;
    #pragma unroll
    for (int d = 1; d < 64; d <<= 1) { int u = __shfl_up(inc, d); if (lane >= d) inc += u; }
    __shared__ int wtot[4];
    if (lane == 63) wtot[wv] = inc;
    __syncthreads();
    int add = 0;
    for (int w = 0; w < wv; ++w) add += wtot[w];
    if (t < NB_SCAN) bpre[t] = inc + add - v;
    if (t == 0) rs[N_NODES] = N_EDGES;
}

__global__ __launch_bounds__(256)
void k_wr(const int* __restrict__ deg, const int* __restrict__ bpre,
          int* __restrict__ rs, int* __restrict__ cur) {
    const int i = blockIdx.x * 256 + threadIdx.x;
    const int lane = threadIdx.x & 63, wv = threadIdx.x >> 6;
    int v = (i < N_NODES) ? deg[i] : 0;
    int inc = v;
    #pragma unroll
    for (int d = 1; d < 64; d <<= 1) { int u = __shfl_up(inc, d); if (lane >= d) inc += u; }
    __shared__ int wtot[4];
    if (lane == 63) wtot[wv] = inc;
    __syncthreads();
    int add = bpre[blockIdx.x];
    for (int w = 0; w < wv; ++w) add += wtot[w];
    if (i < N_NODES) { int excl = inc - v + add; rs[i] = excl; cur[i] = excl; }
}

__global__ __launch_bounds__(256)
void k_fill(const int* __restrict__ dst, int* __restrict__ cur, int* __restrict__ eid) {
    int e = blockIdx.x * 256 + threadIdx.x;
    if (e >= N_EDGES) return;
    int p = atomicAdd(&cur[dst[e]], 1);
    eid[p] = e;
}

// ======================= weight split -> MFMA fragment layout ===============
// Layer table (element offsets into a virtual [sumK x 128] stack):
//   L0 sW1 K=64 @0 | L1 sW2 K=128 @8192 | L2 mW1 K=192 @24576
//   L3 mW2 K=128 @49152 | L4 mW3 K=128 @65536 | L5 mW4 K=128 @81920
// frag idx within layer: ((nt*(K/32)+kt)*4+lq)*128 + colg*8 + i,
// value = W[k*128+col], k=kt*32+lq*8+i, col=nt*16+colg.
#define WTOT 98304
__global__ __launch_bounds__(256)
void k_wsplit(const float* __restrict__ sW1, const float* __restrict__ sW2,
              const float* __restrict__ mW1, const float* __restrict__ mW2,
              const float* __restrict__ mW3, const float* __restrict__ mW4,
              _Float16* __restrict__ wsH, _Float16* __restrict__ wsL) {
    int idx = blockIdx.x * 256 + threadIdx.x;
    if (idx >= WTOT) return;
    const float* W; int base, K;
    if      (idx < 8192)  { W = sW1; base = 0;     K = 64;  }
    else if (idx < 24576) { W = sW2; base = 8192;  K = 128; }
    else if (idx < 49152) { W = mW1; base = 24576; K = 192; }
    else if (idx < 65536) { W = mW2; base = 49152; K = 128; }
    else if (idx < 81920) { W = mW3; base = 65536; K = 128; }
    else                  { W = mW4; base = 81920; K = 128; }
    int local = idx - base;
    int k = local >> 7, col = local & 127;
    int nt = col >> 4, colg = col & 15;
    int kt = k >> 5, lq = (k >> 3) & 3, i = k & 7;
    int fi = base + ((nt * (K >> 5) + kt) * 4 + lq) * 128 + colg * 8 + i;
    float w = W[k * 128 + col];
    _Float16 h = (_Float16)w;
    wsH[fi] = h;
    wsL[fi] = (_Float16)(w - (float)h);
}

// ======================= per-edge kernel-weight GEMM (MFMA, validated) ======
template<typename KWT>
__global__ __launch_bounds__(256)
void k_kw(const float* __restrict__ off2,
          const float* __restrict__ kW1, const float* __restrict__ kb1,
          const float* __restrict__ kW2, const float* __restrict__ kb2,
          KWT* __restrict__ kwbuf) {
    __shared__ _Float16 HsH[64 * 128];
    __shared__ _Float16 HsL[64 * 128];
    const int t  = threadIdx.x;
    const int eb = blockIdx.x * 64;

    {
        const int e  = t & 63;
        const int kq = (t >> 6) * 32;
        float2 o = ((const float2*)off2)[eb + e];
        #pragma unroll
        for (int kk = 0; kk < 32; kk += 8) {
            half8 vh, vl;
            #pragma unroll
            for (int i = 0; i < 8; ++i) {
                int k = kq + kk + i;
                float h = elu_f(fmaf(o.y, kW1[128 + k], fmaf(o.x, kW1[k], kb1[k])));
                _Float16 hh = (_Float16)h;
                vh[i] = hh;
                vl[i] = (_Float16)(h - (float)hh);
            }
            int byte = ((e * 128 + kq + kk) * 2) ^ ((e & 7) << 4);
            *(half8*)((char*)HsH + byte) = vh;
            *(half8*)((char*)HsL + byte) = vl;
        }
    }
    __syncthreads();

    const int lane = t & 63;
    const int wv   = t >> 6;
    const int colg = lane & 15;
    const int lq   = lane >> 4;

    half8 Bh[4], Bl[4];
    #pragma unroll
    for (int kt = 0; kt < 4; ++kt) {
        #pragma unroll
        for (int i = 0; i < 8; ++i) {
            int k = kt * 32 + lq * 8 + i;
            float w = kW2[k * 64 + wv * 16 + colg];
            _Float16 wh = (_Float16)w;
            Bh[kt][i] = wh;
            Bl[kt][i] = (_Float16)(w - (float)wh);
        }
    }
    const float b2 = kb2[wv * 16 + colg];

    #pragma unroll
    for (int m = 0; m < 4; ++m) {
        f32x4 c = {0.f, 0.f, 0.f, 0.f};
        const int row = m * 16 + colg;
        #pragma unroll
        for (int kt = 0; kt < 4; ++kt) {
            int byte = ((row * 128 + kt * 32 + lq * 8) * 2) ^ ((row & 7) << 4);
            half8 Ah = *(const half8*)((const char*)HsH + byte);
            half8 Al = *(const half8*)((const char*)HsL + byte);
            c = __builtin_amdgcn_mfma_f32_16x16x32_f16(Ah, Bh[kt], c, 0, 0, 0);
            c = __builtin_amdgcn_mfma_f32_16x16x32_f16(Ah, Bl[kt], c, 0, 0, 0);
            c = __builtin_amdgcn_mfma_f32_16x16x32_f16(Al, Bh[kt], c, 0, 0, 0);
        }
        #pragma unroll
        for (int r = 0; r < 4; ++r) {
            int e = eb + m * 16 + lq * 4 + r;
            float v = c[r] + b2;
            if constexpr (sizeof(KWT) == 4)
                ((float*)kwbuf)[(size_t)e * 64 + wv * 16 + colg] = v;
            else
                ((__hip_bfloat16*)kwbuf)[(size_t)e * 64 + wv * 16 + colg] = __float2bfloat16(v);
        }
    }
}

// ======================= per-node softmax + gather-aggregate ================
template<typename KWT>
__global__ __launch_bounds__(256)
void k_agg(const float* __restrict__ off2, const int* __restrict__ src,
           const int* __restrict__ eid, const int* __restrict__ rs,
           const float* __restrict__ feat, const KWT* __restrict__ kwbuf,
           float* __restrict__ agg) {
    const int lane = threadIdx.x & 63;
    const int wav  = threadIdx.x >> 6;
    const int gw   = blockIdx.x * 4 + wav;
    const int nw   = gridDim.x * 4;

    for (int n = gw; n < N_NODES; n += nw) {
        const int p0 = rs[n], p1 = rs[n + 1];
        if (p0 == p1) { agg[(size_t)n * 64 + lane] = 0.f; continue; }

        float mx = 0.f;
        for (int p = p0 + lane; p < p1; p += 64) {
            float2 o = ((const float2*)off2)[eid[p]];
            mx = fmaxf(mx, edge_score(o));
        }
        #pragma unroll
        for (int d = 32; d; d >>= 1) mx = fmaxf(mx, __shfl_xor(mx, d));

        float sm = 0.f;
        for (int p = p0 + lane; p < p1; p += 64) {
            float2 o = ((const float2*)off2)[eid[p]];
            sm += expf(edge_score(o) - mx);
        }
        #pragma unroll
        for (int d = 32; d; d >>= 1) sm += __shfl_xor(sm, d);
        const float dinv = 1.f / sm;

        float a0 = 0.f, a1 = 0.f, a2 = 0.f, a3 = 0.f;
        int p = p0;
        for (; p + 4 <= p1; p += 4) {
            const int e0 = eid[p], e1 = eid[p + 1], e2 = eid[p + 2], e3 = eid[p + 3];
            float2 o0 = ((const float2*)off2)[e0];
            float2 o1 = ((const float2*)off2)[e1];
            float2 o2 = ((const float2*)off2)[e2];
            float2 o3 = ((const float2*)off2)[e3];
            const int s0 = src[e0], s1 = src[e1], s2 = src[e2], s3 = src[e3];
            float f0 = feat[(size_t)s0 * 64 + lane];
            float f1 = feat[(size_t)s1 * 64 + lane];
            float f2 = feat[(size_t)s2 * 64 + lane];
            float f3 = feat[(size_t)s3 * 64 + lane];
            float k0, k1, k2, k3;
            if constexpr (sizeof(KWT) == 4) {
                k0 = ((const float*)kwbuf)[(size_t)e0 * 64 + lane];
                k1 = ((const float*)kwbuf)[(size_t)e1 * 64 + lane];
                k2 = ((const float*)kwbuf)[(size_t)e2 * 64 + lane];
                k3 = ((const float*)kwbuf)[(size_t)e3 * 64 + lane];
            } else {
                k0 = __bfloat162float(((const __hip_bfloat16*)kwbuf)[(size_t)e0 * 64 + lane]);
                k1 = __bfloat162float(((const __hip_bfloat16*)kwbuf)[(size_t)e1 * 64 + lane]);
                k2 = __bfloat162float(((const __hip_bfloat16*)kwbuf)[(size_t)e2 * 64 + lane]);
                k3 = __bfloat162float(((const __hip_bfloat16*)kwbuf)[(size_t)e3 * 64 + lane]);
            }
            float w0 = expf(edge_score(o0) - mx) * dinv;
            float w1 = expf(edge_score(o1) - mx) * dinv;
            float w2 = expf(edge_score(o2) - mx) * dinv;
            float w3 = expf(edge_score(o3) - mx) * dinv;
            a0 = fmaf(f0 * w0, k0, a0);
            a1 = fmaf(f1 * w1, k1, a1);
            a2 = fmaf(f2 * w2, k2, a2);
            a3 = fmaf(f3 * w3, k3, a3);
        }
        for (; p < p1; ++p) {
            const int e = eid[p];
            float2 o = ((const float2*)off2)[e];
            float wgt = expf(edge_score(o) - mx) * dinv;
            float f = feat[(size_t)src[e] * 64 + lane];
            float kv;
            if constexpr (sizeof(KWT) == 4) kv = ((const float*)kwbuf)[(size_t)e * 64 + lane];
            else kv = __bfloat162float(((const __hip_bfloat16*)kwbuf)[(size_t)e * 64 + lane]);
            a0 = fmaf(f * wgt, kv, a0);
        }
        agg[(size_t)n * 64 + lane] = (a0 + a1) + (a2 + a3);
    }
}

// ======================= fused node pipeline (MFMA) =========================
// 64 rows/block, 4 waves. Activations in LDS as hi/lo f16, XOR-swizzled.
// Wave wv owns cols [wv*32, wv*32+32). 6 chained layers:
//   self1(K=64,ELU) self2(K=128) | head1(K=192,ELU) head2/3(K=128,ELU) head4(K=128)
// Weights pre-split by k_wsplit into fragment layout.
__device__ __forceinline__
void mm64(const char* XH, const char* XL, const _Float16* __restrict__ WH,
          const _Float16* __restrict__ WL, int K, int lane, int wv, f32x4 c[4][2]) {
    const int colg = lane & 15, lq = lane >> 4;
    #pragma unroll
    for (int m = 0; m < 4; ++m)
        #pragma unroll
        for (int j = 0; j < 2; ++j) c[m][j] = (f32x4){0.f, 0.f, 0.f, 0.f};
    const int KT = K >> 5;
    for (int kt = 0; kt < KT; ++kt) {
        half8 Bh[2], Bl[2], Ah[4], Al[4];
        #pragma unroll
        for (int j = 0; j < 2; ++j) {
            int fo = ((((wv * 2 + j) * KT + kt) * 4 + lq) * 128) + colg * 8;
            Bh[j] = *(const half8*)&WH[fo];
            Bl[j] = *(const half8*)&WL[fo];
        }
        #pragma unroll
        for (int m = 0; m < 4; ++m) {
            int row = m * 16 + colg;
            int byte = ((row * K + kt * 32 + lq * 8) * 2) ^ ((row & 7) << 4);
            Ah[m] = *(const half8*)(XH + byte);
            Al[m] = *(const half8*)(XL + byte);
        }
        #pragma unroll
        for (int m = 0; m < 4; ++m)
            #pragma unroll
            for (int j = 0; j < 2; ++j) {
                c[m][j] = __builtin_amdgcn_mfma_f32_16x16x32_f16(Ah[m], Bh[j], c[m][j], 0, 0, 0);
                c[m][j] = __builtin_amdgcn_mfma_f32_16x16x32_f16(Ah[m], Bl[j], c[m][j], 0, 0, 0);
                c = c; // no-op
                c[m][j] = __builtin_amdgcn_mfma_f32_16x16x32_f16(Al[m], Bh[j], c[m][j], 0, 0, 0);
            }
    }
}

__device__ __forceinline__
void epi_lds(char* XH, char* XL, int Knext, int colOff, int lane, int wv,
             f32x4 c[4][2], const float* __restrict__ bias, bool do_elu) {
    const int colg = lane & 15, lq = lane >> 4;
    float bj[2] = { bias[wv * 32 + colg], bias[wv * 32 + 16 + colg] };
    #pragma unroll
    for (int m = 0; m < 4; ++m)
        #pragma unroll
        for (int j = 0; j < 2; ++j) {
            int col = colOff + wv * 32 + j * 16 + colg;
            #pragma unroll
            for (int r = 0; r < 4; ++r) {
                int row = m * 16 + lq * 4 + r;
                float v = c[m][j][r] + bj[j];
                if (do_elu) v = elu_f(v);
                _Float16 h = (_Float16)v;
                int byte = ((row * Knext + col) * 2) ^ ((row & 7) << 4);
                *(_Float16*)(XH + byte) = h;
                *(_Float16*)(XL + byte) = (_Float16)(v - (float)h);
            }
        }
}

__global__ __launch_bounds__(256)
void k_node(const float* __restrict__ feat, const float* __restrict__ agg,
            const _Float16* __restrict__ wsH, const _Float16* __restrict__ wsL,
            const float* __restrict__ sb1, const float* __restrict__ sb2,
            const float* __restrict__ mb1, const float* __restrict__ mb2,
            const float* __restrict__ mb3, const float* __restrict__ mb4,
            float* __restrict__ out) {
    __shared__ _Float16 XH[64 * 192];   // 24 KB
    __shared__ _Float16 XL[64 * 192];   // 24 KB
    const int t = threadIdx.x;
    const int lane = t & 63, wv = t >> 6;
    const int row0 = blockIdx.x * 64;
    f32x4 c[4][2];

    // ---- stage feat[64][64] -> X (K=64), hi/lo, swizzled ----
    {
        int r = t >> 2, c4 = (t & 3) * 4;   // 4 threads/row, 4 float4 each
        #pragma unroll
        for (int q = 0; q < 4; ++q) {
            int col = (c4 + q) * 4;
            float4 v = make_float4(0.f, 0.f, 0.f, 0.f);
            if (row0 + r < N_NODES) v = *(const float4*)&feat[(size_t)(row0 + r) * 64 + col];
            _Float16 h4h[4], h4l[4];
            float vv[4] = {v.x, v.y, v.z, v.w};
            #pragma unroll
            for (int i = 0; i < 4; ++i) {
                _Float16 h = (_Float16)vv[i];
                h4h[i] = h; h4l[i] = (_Float16)(vv[i] - (float)h);
            }
            int byte = ((r * 64 + col) * 2) ^ ((r & 7) << 4);
            *(ulong1*)((char*)XH + byte) = *(ulong1*)h4h;
            *(ulong1*)((char*)XL + byte) = *(ulong1*)h4l;
        }
    }
    __syncthreads();

    // ---- self L1: K=64, ELU -> X[64][128] ----
    mm64((const char*)XH, (const char*)XL, wsH + 0, wsL + 0, 64, lane, wv, c);
    __syncthreads();
    epi_lds((char*)XH, (char*)XL, 128, 0, lane, wv, c, sb1, true);
    __syncthreads();

    // ---- self L2: K=128, no ELU -> selfb, placed in X[64][192] cols 64..191;
    //      agg staged into cols 0..63 ----
    mm64((const char*)XH, (const char*)XL, wsH + 8192, wsL + 8192, 128, lane, wv, c);
    __syncthreads();
    epi_lds((char*)XH, (char*)XL, 192, 64, lane, wv, c, sb2, false);
    {
        int r = t >> 2, c4 = (t & 3) * 4;
        #pragma unroll
        for (int q = 0; q < 4; ++q) {
            int col = (c4 + q) * 4;
            float4 v = make_float4(0.f, 0.f, 0.f, 0.f);
            if (row0 + r < N_NODES) v = *(const float4*)&agg[(size_t)(row0 + r) * 64 + col];
            _Float16 h4h[4], h4l[4];
            float vv[4] = {v.x, v.y, v.z, v.w};
            #pragma unroll
            for (int i = 0; i < 4; ++i) {
                _Float16 h = (_Float16)vv[i];
                h4h[i] = h; h4l[i] = (_Float16)(vv[i] - (float)h);
            }
            int byte = ((r * 192 + col) * 2) ^ ((r & 7) << 4);
            *(ulong1*)((char*)XH + byte) = *(ulong1*)h4h;
            *(ulong1*)((char*)XL + byte) = *(ulong1*)h4l;
        }
    }
    __syncthreads();

    // ---- head L1: K=192, ELU -> X[64][128] ----
    mm64((const char*)XH, (const char*)XL, wsH + 24576, wsL + 24576, 192, lane, wv, c);
    __syncthreads();
    epi_lds((char*)XH, (char*)XL, 128, 0, lane, wv, c, mb1, true);
    __syncthreads();

    // ---- head L2: K=128, ELU ----
    mm64((const char*)XH, (const char*)XL, wsH + 49152, wsL + 49152, 128, lane, wv, c);
    __syncthreads();
    epi_lds((char*)XH, (char*)XL, 128, 0, lane, wv, c, mb2, true);
    __syncthreads();

    // ---- head L3: K=128, ELU ----
    mm64((const char*)XH, (const char*)XL, wsH + 65536, wsL + 65536, 128, lane, wv, c);
    __syncthreads();
    epi_lds((char*)XH, (char*)XL, 128, 0, lane, wv, c, mb3, true);
    __syncthreads();

    // ---- head L4: K=128 -> global out ----
    mm64((const char*)XH, (const char*)XL, wsH + 81920, wsL + 81920, 128, lane, wv, c);
    {
        const int colg = lane & 15, lq = lane >> 4;
        float bj[2] = { mb4[wv * 32 + colg], mb4[wv * 32 + 16 + colg] };
        #pragma unroll
        for (int m = 0; m < 4; ++m)
            #pragma unroll
            for (int j = 0; j < 2; ++j) {
                int col = wv * 32 + j * 16 + colg;
                #pragma unroll
                for (int r = 0; r < 4; ++r) {
                    int row = row0 + m * 16 + lq * 4 + r;
                    if (row < N_NODES)
                        out[(size_t)row * 128 + col] = c[m][j][r] + bj[j];
                }
            }
    }
}

// ============================================================================
extern "C" void kernel_launch(void* const* d_in, const int* in_sizes, int n_in,
                              void* d_out, int out_size, void* d_ws, size_t ws_size,
                              hipStream_t stream) {
    (void)in_sizes; (void)n_in; (void)out_size;
    const float* feat = (const float*)d_in[0];
    const float* off2 = (const float*)d_in[1];
    const int*   src  = (const int*)d_in[2];
    const int*   dst  = (const int*)d_in[3];
    const float* kW1  = (const float*)d_in[4];
    const float* kb1  = (const float*)d_in[5];
    const float* kW2  = (const float*)d_in[6];
    const float* kb2  = (const float*)d_in[7];
    const float* sW1  = (const float*)d_in[8];
    const float* sb1  = (const float*)d_in[9];
    const float* sW2  = (const float*)d_in[10];
    const float* sb2  = (const float*)d_in[11];
    const float* mW1  = (const float*)d_in[12];
    const float* mb1  = (const float*)d_in[13];
    const float* mW2  = (const float*)d_in[14];
    const float* mb2  = (const float*)d_in[15];
    const float* mW3  = (const float*)d_in[16];
    const float* mb3  = (const float*)d_in[17];
    const float* mW4  = (const float*)d_in[18];
    const float* mb4  = (const float*)d_in[19];

    char* ws = (char*)d_ws;
    size_t off = 0;
    auto alloc = [&](size_t bytes) -> void* {
        void* p = ws + off;
        off += (bytes + 255) & ~(size_t)255;
        return p;
    };
    int*   deg   = (int*)alloc((size_t)N_NODES * 4);
    int*   rs    = (int*)alloc((size_t)(N_NODES + 8) * 4);
    int*   cur   = (int*)alloc((size_t)N_NODES * 4);
    int*   bsum  = (int*)alloc((size_t)NB_SCAN * 4);
    int*   bpre  = (int*)alloc((size_t)NB_SCAN * 4);
    int*   eid   = (int*)alloc((size_t)N_EDGES * 4);
    float* agg   = (float*)alloc((size_t)N_NODES * 64 * 4);
    _Float16* wsH = (_Float16*)alloc((size_t)WTOT * 2);
    _Float16* wsL = (_Float16*)alloc((size_t)WTOT * 2);
    const size_t kw_f32_bytes = (size_t)N_EDGES * 64 * 4;
    const bool kw_f32 = (ws_size - off) >= kw_f32_bytes;
    void* kwbuf = alloc(kw_f32 ? kw_f32_bytes : kw_f32_bytes / 2);

    hipMemsetAsync(deg, 0, (size_t)N_NODES * 4, stream);

    const int EB = (N_EDGES + 255) / 256;   // 3125
    const int KB = N_EDGES / 64;            // 12500
    const int GB = (N_NODES + 63) / 64;     // 782

    k_deg   <<<EB, 256, 0, stream>>>(dst, deg);
    k_bsum  <<<NB_SCAN, 256, 0, stream>>>(deg, bsum);
    k_bscan <<<1, 256, 0, stream>>>(bsum, bpre, rs);
    k_wr    <<<NB_SCAN, 256, 0, stream>>>(deg, bpre, rs, cur);
    k_fill  <<<EB, 256, 0, stream>>>(dst, cur, eid);
    k_wsplit<<<(WTOT + 255) / 256, 256, 0, stream>>>(sW1, sW2, mW1, mW2, mW3, mW4, wsH, wsL);

    if (kw_f32) {
        k_kw<float> <<<KB, 256, 0, stream>>>(off2, kW1, kb1, kW2, kb2, (float*)kwbuf);
        k_agg<float><<<2048, 256, 0, stream>>>(off2, src, eid, rs, feat, (const float*)kwbuf, agg);
    } else {
        k_kw<__hip_bfloat16> <<<KB, 256, 0, stream>>>(off2, kW1, kb1, kW2, kb2, (__hip_bfloat16*)kwbuf);
        k_agg<__hip_bfloat16><<<2048, 256, 0, stream>>>(off2, src, eid, rs, feat,
                                                        (const __hip_bfloat16*)kwbuf, agg);
    }

    k_node<<<GB, 256, 0, stream>>>(feat, agg, wsH, wsL, sb1, sb2, mb1, mb2, mb3, mb4,
                                   (float*)d_out);
}

// Round 7
// 379.831 us; speedup vs baseline: 3.1330x; 1.0141x over previous
//
#include <hip/hip_runtime.h>
#include <hip/hip_bf16.h>
#include <math.h>

#define N_NODES 50000
#define N_EDGES 800000
#define NB_SCAN ((N_NODES + 255) / 256)   // 196

typedef _Float16 half8 __attribute__((ext_vector_type(8)));
typedef _Float16 half4 __attribute__((ext_vector_type(4)));
typedef float f32x4 __attribute__((ext_vector_type(4)));

__device__ __forceinline__ float elu_f(float x) { return x > 0.f ? x : expm1f(x); }
__device__ __forceinline__ float edge_score(float2 o) {
    return 1.f / (fabsf(o.x) + fabsf(o.y) + 0.001f);   // > 0 always
}

// ======================= CSR build =========================================
__global__ __launch_bounds__(256)
void k_deg(const int* __restrict__ dst, int* __restrict__ deg) {
    int e = blockIdx.x * 256 + threadIdx.x;
    if (e >= N_EDGES) return;
    atomicAdd(&deg[dst[e]], 1);
}

__global__ __launch_bounds__(256)
void k_bsum(const int* __restrict__ deg, int* __restrict__ bsum) {
    int i = blockIdx.x * 256 + threadIdx.x;
    int v = (i < N_NODES) ? deg[i] : 0;
    #pragma unroll
    for (int d = 32; d; d >>= 1) v += __shfl_xor(v, d);
    __shared__ int ws[4];
    if ((threadIdx.x & 63) == 0) ws[threadIdx.x >> 6] = v;
    __syncthreads();
    if (threadIdx.x == 0) bsum[blockIdx.x] = ws[0] + ws[1] + ws[2] + ws[3];
}

__global__ __launch_bounds__(256)
void k_bscan(const int* __restrict__ bsum, int* __restrict__ bpre, int* __restrict__ rs) {
    const int t = threadIdx.x, lane = t & 63, wv = t >> 6;
    int v = (t < NB_SCAN) ? bsum[t] : 0;
    int inc = v;
    #pragma unroll
    for (int d = 1; d < 64; d <<= 1) { int u = __shfl_up(inc, d); if (lane >= d) inc += u; }
    __shared__ int wtot[4];
    if (lane == 63) wtot[wv] = inc;
    __syncthreads();
    int add = 0;
    for (int w = 0; w < wv; ++w) add += wtot[w];
    if (t < NB_SCAN) bpre[t] = inc + add - v;
    if (t == 0) rs[N_NODES] = N_EDGES;
}

__global__ __launch_bounds__(256)
void k_wr(const int* __restrict__ deg, const int* __restrict__ bpre,
          int* __restrict__ rs, int* __restrict__ cur) {
    const int i = blockIdx.x * 256 + threadIdx.x;
    const int lane = threadIdx.x & 63, wv = threadIdx.x >> 6;
    int v = (i < N_NODES) ? deg[i] : 0;
    int inc = v;
    #pragma unroll
    for (int d = 1; d < 64; d <<= 1) { int u = __shfl_up(inc, d); if (lane >= d) inc += u; }
    __shared__ int wtot[4];
    if (lane == 63) wtot[wv] = inc;
    __syncthreads();
    int add = bpre[blockIdx.x];
    for (int w = 0; w < wv; ++w) add += wtot[w];
    if (i < N_NODES) { int excl = inc - v + add; rs[i] = excl; cur[i] = excl; }
}

__global__ __launch_bounds__(256)
void k_fill(const int* __restrict__ dst, int* __restrict__ cur, int* __restrict__ eid) {
    int e = blockIdx.x * 256 + threadIdx.x;
    if (e >= N_EDGES) return;
    int p = atomicAdd(&cur[dst[e]], 1);
    eid[p] = e;
}

// ======================= node-weight split -> MFMA fragment layout ==========
// L0 sW1 K=64 @0 | L1 sW2 K=128 @8192 | L2 mW1 K=192 @24576
// L3 mW2 K=128 @49152 | L4 mW3 K=128 @65536 | L5 mW4 K=128 @81920
#define WTOT 98304
__global__ __launch_bounds__(256)
void k_wsplit(const float* __restrict__ sW1, const float* __restrict__ sW2,
              const float* __restrict__ mW1, const float* __restrict__ mW2,
              const float* __restrict__ mW3, const float* __restrict__ mW4,
              _Float16* __restrict__ wsH, _Float16* __restrict__ wsL) {
    int idx = blockIdx.x * 256 + threadIdx.x;
    if (idx >= WTOT) return;
    const float* W; int base, K;
    if      (idx < 8192)  { W = sW1; base = 0;     K = 64;  }
    else if (idx < 24576) { W = sW2; base = 8192;  K = 128; }
    else if (idx < 49152) { W = mW1; base = 24576; K = 192; }
    else if (idx < 65536) { W = mW2; base = 49152; K = 128; }
    else if (idx < 81920) { W = mW3; base = 65536; K = 128; }
    else                  { W = mW4; base = 81920; K = 128; }
    int local = idx - base;
    int k = local >> 7, col = local & 127;
    int nt = col >> 4, colg = col & 15;
    int kt = k >> 5, lq = (k >> 3) & 3, i = k & 7;
    int fi = base + ((nt * (K >> 5) + kt) * 4 + lq) * 128 + colg * 8 + i;
    float w = W[k * 128 + col];
    _Float16 h = (_Float16)w;
    wsH[fi] = h;
    wsL[fi] = (_Float16)(w - (float)h);
}

// ======================= kW2 split -> A-fragment layout =====================
// frag idx: ((jt*4+kt)*4+lq)*128 + colg*8 + i  -> kW2[(kt*32+lq*8+i)*64 + jt*16+colg]
#define KW2TOT 8192
__global__ __launch_bounds__(256)
void k_kwsplit2(const float* __restrict__ kW2,
                _Float16* __restrict__ wkH, _Float16* __restrict__ wkL) {
    int idx = blockIdx.x * 256 + threadIdx.x;
    if (idx >= KW2TOT) return;
    int i = idx & 7, colg = (idx >> 3) & 15;
    int lq = (idx >> 7) & 3, kt = (idx >> 9) & 3, jt = idx >> 11;
    int k = kt * 32 + lq * 8 + i;
    int j = jt * 16 + colg;
    float w = kW2[k * 64 + j];
    _Float16 h = (_Float16)w;
    wkH[idx] = h;
    wkL[idx] = (_Float16)(w - (float)h);
}

// ======================= per-edge kernel-weight GEMM (no-LDS MFMA) ==========
// 4 waves/block, 64 edges/wave (256 edges/block). Swapped operands:
//   A := kW2 fragments (j-indexed, pre-split hi/lo global, coalesced b128)
//   B := H fragments (edge-indexed) computed DIRECTLY in registers:
//        lane computes h[e = et*16+colg][k = kt*32+lq*8+i] — exactly its frag.
// D[row=j-tile][col=edge]: lane holds 4 consecutive j per (et,jt) -> 8B f16 store.
// No LDS, no barriers, no bank conflicts. 3-term hi/lo split (fp32-accurate).
__global__ __launch_bounds__(256)
void k_kw(const float* __restrict__ off2,
          const float* __restrict__ kW1, const float* __restrict__ kb1,
          const _Float16* __restrict__ wkH, const _Float16* __restrict__ wkL,
          const float* __restrict__ kb2, _Float16* __restrict__ kwbuf) {
    const int t = threadIdx.x;
    const int lane = t & 63, wv = t >> 6;
    const int eb = blockIdx.x * 256 + wv * 64;
    const int colg = lane & 15, lq = lane >> 4;

    float2 o[4];
    #pragma unroll
    for (int et = 0; et < 4; ++et)
        o[et] = ((const float2*)off2)[eb + et * 16 + colg];

    f32x4 c[4][4];   // [et][jt]
    #pragma unroll
    for (int et = 0; et < 4; ++et)
        #pragma unroll
        for (int jt = 0; jt < 4; ++jt) c[et][jt] = (f32x4){0.f, 0.f, 0.f, 0.f};

    #pragma unroll
    for (int kt = 0; kt < 4; ++kt) {
        const int k0 = kt * 32 + lq * 8;
        float4 a0 = *(const float4*)&kW1[k0];
        float4 a1 = *(const float4*)&kW1[k0 + 4];
        float4 b0 = *(const float4*)&kW1[128 + k0];
        float4 b1 = *(const float4*)&kW1[128 + k0 + 4];
        float4 c0 = *(const float4*)&kb1[k0];
        float4 c1 = *(const float4*)&kb1[k0 + 4];
        const float wa[8] = {a0.x, a0.y, a0.z, a0.w, a1.x, a1.y, a1.z, a1.w};
        const float wb[8] = {b0.x, b0.y, b0.z, b0.w, b1.x, b1.y, b1.z, b1.w};
        const float bb[8] = {c0.x, c0.y, c0.z, c0.w, c1.x, c1.y, c1.z, c1.w};

        half8 Bh[4], Bl[4];
        #pragma unroll
        for (int et = 0; et < 4; ++et) {
            #pragma unroll
            for (int i = 0; i < 8; ++i) {
                float h = elu_f(fmaf(o[et].y, wb[i], fmaf(o[et].x, wa[i], bb[i])));
                _Float16 hh = (_Float16)h;
                Bh[et][i] = hh;
                Bl[et][i] = (_Float16)(h - (float)hh);
            }
        }
        #pragma unroll
        for (int jt = 0; jt < 4; ++jt) {
            int fo = ((jt * 4 + kt) * 4 + lq) * 128 + colg * 8;
            half8 Ah = *(const half8*)&wkH[fo];
            half8 Al = *(const half8*)&wkL[fo];
            #pragma unroll
            for (int et = 0; et < 4; ++et) {
                c[et][jt] = __builtin_amdgcn_mfma_f32_16x16x32_f16(Ah, Bh[et], c[et][jt], 0, 0, 0);
                c[et][jt] = __builtin_amdgcn_mfma_f32_16x16x32_f16(Ah, Bl[et], c[et][jt], 0, 0, 0);
                c[et][jt] = __builtin_amdgcn_mfma_f32_16x16x32_f16(Al, Bh[et], c[et][jt], 0, 0, 0);
            }
        }
    }

    // epilogue: D[row=jt*16+lq*4+r][col=et*16+colg]; 4 consecutive j -> 8B store
    #pragma unroll
    for (int jt = 0; jt < 4; ++jt) {
        const int j0 = jt * 16 + lq * 4;
        float4 bv = *(const float4*)&kb2[j0];
        const float bias4[4] = {bv.x, bv.y, bv.z, bv.w};
        #pragma unroll
        for (int et = 0; et < 4; ++et) {
            const int e = eb + et * 16 + colg;
            half4 v;
            #pragma unroll
            for (int r = 0; r < 4; ++r) v[r] = (_Float16)(c[et][jt][r] + bias4[r]);
            *(half4*)&kwbuf[(size_t)e * 64 + j0] = v;
        }
    }
}

// ======================= per-node softmax + gather-aggregate ================
__global__ __launch_bounds__(256)
void k_agg(const float* __restrict__ off2, const int* __restrict__ src,
           const int* __restrict__ eid, const int* __restrict__ rs,
           const float* __restrict__ feat, const _Float16* __restrict__ kwbuf,
           float* __restrict__ agg) {
    const int lane = threadIdx.x & 63;
    const int wav  = threadIdx.x >> 6;
    const int gw   = blockIdx.x * 4 + wav;
    const int nw   = gridDim.x * 4;

    for (int n = gw; n < N_NODES; n += nw) {
        const int p0 = rs[n], p1 = rs[n + 1];
        if (p0 == p1) { agg[(size_t)n * 64 + lane] = 0.f; continue; }

        float mx = 0.f;
        for (int p = p0 + lane; p < p1; p += 64) {
            float2 o = ((const float2*)off2)[eid[p]];
            mx = fmaxf(mx, edge_score(o));
        }
        #pragma unroll
        for (int d = 32; d; d >>= 1) mx = fmaxf(mx, __shfl_xor(mx, d));

        float sm = 0.f;
        for (int p = p0 + lane; p < p1; p += 64) {
            float2 o = ((const float2*)off2)[eid[p]];
            sm += expf(edge_score(o) - mx);
        }
        #pragma unroll
        for (int d = 32; d; d >>= 1) sm += __shfl_xor(sm, d);
        const float dinv = 1.f / sm;

        float a0 = 0.f, a1 = 0.f, a2 = 0.f, a3 = 0.f;
        int p = p0;
        for (; p + 4 <= p1; p += 4) {
            const int e0 = eid[p], e1 = eid[p + 1], e2 = eid[p + 2], e3 = eid[p + 3];
            float2 o0 = ((const float2*)off2)[e0];
            float2 o1 = ((const float2*)off2)[e1];
            float2 o2 = ((const float2*)off2)[e2];
            float2 o3 = ((const float2*)off2)[e3];
            const int s0 = src[e0], s1 = src[e1], s2 = src[e2], s3 = src[e3];
            float f0 = feat[(size_t)s0 * 64 + lane];
            float f1 = feat[(size_t)s1 * 64 + lane];
            float f2 = feat[(size_t)s2 * 64 + lane];
            float f3 = feat[(size_t)s3 * 64 + lane];
            float k0 = (float)kwbuf[(size_t)e0 * 64 + lane];
            float k1 = (float)kwbuf[(size_t)e1 * 64 + lane];
            float k2 = (float)kwbuf[(size_t)e2 * 64 + lane];
            float k3 = (float)kwbuf[(size_t)e3 * 64 + lane];
            float w0 = expf(edge_score(o0) - mx) * dinv;
            float w1 = expf(edge_score(o1) - mx) * dinv;
            float w2 = expf(edge_score(o2) - mx) * dinv;
            float w3 = expf(edge_score(o3) - mx) * dinv;
            a0 = fmaf(f0 * w0, k0, a0);
            a1 = fmaf(f1 * w1, k1, a1);
            a2 = fmaf(f2 * w2, k2, a2);
            a3 = fmaf(f3 * w3, k3, a3);
        }
        for (; p < p1; ++p) {
            const int e = eid[p];
            float2 o = ((const float2*)off2)[e];
            float wgt = expf(edge_score(o) - mx) * dinv;
            float f = feat[(size_t)src[e] * 64 + lane];
            float kv = (float)kwbuf[(size_t)e * 64 + lane];
            a0 = fmaf(f * wgt, kv, a0);
        }
        agg[(size_t)n * 64 + lane] = (a0 + a1) + (a2 + a3);
    }
}

// ======================= fused node pipeline (MFMA) =========================
__device__ __forceinline__
void mm64(const char* XH, const char* XL, const _Float16* __restrict__ WH,
          const _Float16* __restrict__ WL, int K, int lane, int wv, f32x4 c[4][2]) {
    const int colg = lane & 15, lq = lane >> 4;
    #pragma unroll
    for (int m = 0; m < 4; ++m)
        #pragma unroll
        for (int j = 0; j < 2; ++j) c[m][j] = (f32x4){0.f, 0.f, 0.f, 0.f};
    const int KT = K >> 5;
    for (int kt = 0; kt < KT; ++kt) {
        half8 Bh[2], Bl[2], Ah[4], Al[4];
        #pragma unroll
        for (int j = 0; j < 2; ++j) {
            int fo = ((((wv * 2 + j) * KT + kt) * 4 + lq) * 128) + colg * 8;
            Bh[j] = *(const half8*)&WH[fo];
            Bl[j] = *(const half8*)&WL[fo];
        }
        #pragma unroll
        for (int m = 0; m < 4; ++m) {
            int row = m * 16 + colg;
            int byte = ((row * K + kt * 32 + lq * 8) * 2) ^ ((row & 7) << 4);
            Ah[m] = *(const half8*)(XH + byte);
            Al[m] = *(const half8*)(XL + byte);
        }
        #pragma unroll
        for (int m = 0; m < 4; ++m)
            #pragma unroll
            for (int j = 0; j < 2; ++j) {
                c[m][j] = __builtin_amdgcn_mfma_f32_16x16x32_f16(Ah[m], Bh[j], c[m][j], 0, 0, 0);
                c[m][j] = __builtin_amdgcn_mfma_f32_16x16x32_f16(Ah[m], Bl[j], c[m][j], 0, 0, 0);
                c[m][j] = __builtin_amdgcn_mfma_f32_16x16x32_f16(Al[m], Bh[j], c[m][j], 0, 0, 0);
            }
    }
}

__device__ __forceinline__
void epi_lds(char* XH, char* XL, int Knext, int colOff, int lane, int wv,
             f32x4 c[4][2], const float* __restrict__ bias, bool do_elu) {
    const int colg = lane & 15, lq = lane >> 4;
    float bj[2] = { bias[wv * 32 + colg], bias[wv * 32 + 16 + colg] };
    #pragma unroll
    for (int m = 0; m < 4; ++m)
        #pragma unroll
        for (int j = 0; j < 2; ++j) {
            int col = colOff + wv * 32 + j * 16 + colg;
            #pragma unroll
            for (int r = 0; r < 4; ++r) {
                int row = m * 16 + lq * 4 + r;
                float v = c[m][j][r] + bj[j];
                if (do_elu) v = elu_f(v);
                _Float16 h = (_Float16)v;
                int byte = ((row * Knext + col) * 2) ^ ((row & 7) << 4);
                *(_Float16*)(XH + byte) = h;
                *(_Float16*)(XL + byte) = (_Float16)(v - (float)h);
            }
        }
}

__global__ __launch_bounds__(256)
void k_node(const float* __restrict__ feat, const float* __restrict__ agg,
            const _Float16* __restrict__ wsH, const _Float16* __restrict__ wsL,
            const float* __restrict__ sb1, const float* __restrict__ sb2,
            const float* __restrict__ mb1, const float* __restrict__ mb2,
            const float* __restrict__ mb3, const float* __restrict__ mb4,
            float* __restrict__ out) {
    __shared__ _Float16 XH[64 * 192];
    __shared__ _Float16 XL[64 * 192];
    const int t = threadIdx.x;
    const int lane = t & 63, wv = t >> 6;
    const int row0 = blockIdx.x * 64;
    f32x4 c[4][2];

    {
        int r = t >> 2, c4 = (t & 3) * 4;
        #pragma unroll
        for (int q = 0; q < 4; ++q) {
            int col = (c4 + q) * 4;
            float4 v = make_float4(0.f, 0.f, 0.f, 0.f);
            if (row0 + r < N_NODES) v = *(const float4*)&feat[(size_t)(row0 + r) * 64 + col];
            _Float16 h4h[4], h4l[4];
            float vv[4] = {v.x, v.y, v.z, v.w};
            #pragma unroll
            for (int i = 0; i < 4; ++i) {
                _Float16 h = (_Float16)vv[i];
                h4h[i] = h; h4l[i] = (_Float16)(vv[i] - (float)h);
            }
            int byte = ((r * 64 + col) * 2) ^ ((r & 7) << 4);
            *(ulong1*)((char*)XH + byte) = *(ulong1*)h4h;
            *(ulong1*)((char*)XL + byte) = *(ulong1*)h4l;
        }
    }
    __syncthreads();

    mm64((const char*)XH, (const char*)XL, wsH + 0, wsL + 0, 64, lane, wv, c);
    __syncthreads();
    epi_lds((char*)XH, (char*)XL, 128, 0, lane, wv, c, sb1, true);
    __syncthreads();

    mm64((const char*)XH, (const char*)XL, wsH + 8192, wsL + 8192, 128, lane, wv, c);
    __syncthreads();
    epi_lds((char*)XH, (char*)XL, 192, 64, lane, wv, c, sb2, false);
    {
        int r = t >> 2, c4 = (t & 3) * 4;
        #pragma unroll
        for (int q = 0; q < 4; ++q) {
            int col = (c4 + q) * 4;
            float4 v = make_float4(0.f, 0.f, 0.f, 0.f);
            if (row0 + r < N_NODES) v = *(const float4*)&agg[(size_t)(row0 + r) * 64 + col];
            _Float16 h4h[4], h4l[4];
            float vv[4] = {v.x, v.y, v.z, v.w};
            #pragma unroll
            for (int i = 0; i < 4; ++i) {
                _Float16 h = (_Float16)vv[i];
                h4h[i] = h; h4l[i] = (_Float16)(vv[i] - (float)h);
            }
            int byte = ((r * 192 + col) * 2) ^ ((r & 7) << 4);
            *(ulong1*)((char*)XH + byte) = *(ulong1*)h4h;
            *(ulong1*)((char*)XL + byte) = *(ulong1*)h4l;
        }
    }
    __syncthreads();

    mm64((const char*)XH, (const char*)XL, wsH + 24576, wsL + 24576, 192, lane, wv, c);
    __syncthreads();
    epi_lds((char*)XH, (char*)XL, 128, 0, lane, wv, c, mb1, true);
    __syncthreads();

    mm64((const char*)XH, (const char*)XL, wsH + 49152, wsL + 49152, 128, lane, wv, c);
    __syncthreads();
    epi_lds((char*)XH, (char*)XL, 128, 0, lane, wv, c, mb2, true);
    __syncthreads();

    mm64((const char*)XH, (const char*)XL, wsH + 65536, wsL + 65536, 128, lane, wv, c);
    __syncthreads();
    epi_lds((char*)XH, (char*)XL, 128, 0, lane, wv, c, mb3, true);
    __syncthreads();

    mm64((const char*)XH, (const char*)XL, wsH + 81920, wsL + 81920, 128, lane, wv, c);
    {
        const int colg = lane & 15, lq = lane >> 4;
        float bj[2] = { mb4[wv * 32 + colg], mb4[wv * 32 + 16 + colg] };
        #pragma unroll
        for (int m = 0; m < 4; ++m)
            #pragma unroll
            for (int j = 0; j < 2; ++j) {
                int col = wv * 32 + j * 16 + colg;
                #pragma unroll
                for (int r = 0; r < 4; ++r) {
                    int row = row0 + m * 16 + lq * 4 + r;
                    if (row < N_NODES)
                        out[(size_t)row * 128 + col] = c[m][j][r] + bj[j];
                }
            }
    }
}

// ============================================================================
extern "C" void kernel_launch(void* const* d_in, const int* in_sizes, int n_in,
                              void* d_out, int out_size, void* d_ws, size_t ws_size,
                              hipStream_t stream) {
    (void)in_sizes; (void)n_in; (void)out_size; (void)ws_size;
    const float* feat = (const float*)d_in[0];
    const float* off2 = (const float*)d_in[1];
    const int*   src  = (const int*)d_in[2];
    const int*   dst  = (const int*)d_in[3];
    const float* kW1  = (const float*)d_in[4];
    const float* kb1  = (const float*)d_in[5];
    const float* kW2  = (const float*)d_in[6];
    const float* kb2  = (const float*)d_in[7];
    const float* sW1  = (const float*)d_in[8];
    const float* sb1  = (const float*)d_in[9];
    const float* sW2  = (const float*)d_in[10];
    const float* sb2  = (const float*)d_in[11];
    const float* mW1  = (const float*)d_in[12];
    const float* mb1  = (const float*)d_in[13];
    const float* mW2  = (const float*)d_in[14];
    const float* mb2  = (const float*)d_in[15];
    const float* mW3  = (const float*)d_in[16];
    const float* mb3  = (const float*)d_in[17];
    const float* mW4  = (const float*)d_in[18];
    const float* mb4  = (const float*)d_in[19];

    char* ws = (char*)d_ws;
    size_t off = 0;
    auto alloc = [&](size_t bytes) -> void* {
        void* p = ws + off;
        off += (bytes + 255) & ~(size_t)255;
        return p;
    };
    int*   deg   = (int*)alloc((size_t)N_NODES * 4);
    int*   rs    = (int*)alloc((size_t)(N_NODES + 8) * 4);
    int*   cur   = (int*)alloc((size_t)N_NODES * 4);
    int*   bsum  = (int*)alloc((size_t)NB_SCAN * 4);
    int*   bpre  = (int*)alloc((size_t)NB_SCAN * 4);
    int*   eid   = (int*)alloc((size_t)N_EDGES * 4);
    float* agg   = (float*)alloc((size_t)N_NODES * 64 * 4);
    _Float16* wsH = (_Float16*)alloc((size_t)WTOT * 2);
    _Float16* wsL = (_Float16*)alloc((size_t)WTOT * 2);
    _Float16* wkH = (_Float16*)alloc((size_t)KW2TOT * 2);
    _Float16* wkL = (_Float16*)alloc((size_t)KW2TOT * 2);
    _Float16* kwbuf = (_Float16*)alloc((size_t)N_EDGES * 64 * 2);

    hipMemsetAsync(deg, 0, (size_t)N_NODES * 4, stream);

    const int EB = (N_EDGES + 255) / 256;   // 3125
    const int GB = (N_NODES + 63) / 64;     // 782

    k_deg     <<<EB, 256, 0, stream>>>(dst, deg);
    k_bsum    <<<NB_SCAN, 256, 0, stream>>>(deg, bsum);
    k_bscan   <<<1, 256, 0, stream>>>(bsum, bpre, rs);
    k_wr      <<<NB_SCAN, 256, 0, stream>>>(deg, bpre, rs, cur);
    k_fill    <<<EB, 256, 0, stream>>>(dst, cur, eid);
    k_wsplit  <<<(WTOT + 255) / 256, 256, 0, stream>>>(sW1, sW2, mW1, mW2, mW3, mW4, wsH, wsL);
    k_kwsplit2<<<(KW2TOT + 255) / 256, 256, 0, stream>>>(kW2, wkH, wkL);

    k_kw <<<N_EDGES / 256, 256, 0, stream>>>(off2, kW1, kb1, wkH, wkL, kb2, kwbuf);
    k_agg<<<2048, 256, 0, stream>>>(off2, src, eid, rs, feat, kwbuf, agg);

    k_node<<<GB, 256, 0, stream>>>(feat, agg, wsH, wsL, sb1, sb2, mb1, mb2, mb3, mb4,
                                   (float*)d_out);
}

// Round 8
// 278.884 us; speedup vs baseline: 4.2671x; 1.3620x over previous
//
#include <hip/hip_runtime.h>
#include <hip/hip_bf16.h>
#include <math.h>

#define N_NODES 50000
#define N_EDGES 800000
#define NB_SCAN ((N_NODES + 255) / 256)   // 196

typedef _Float16 half8 __attribute__((ext_vector_type(8)));
typedef _Float16 half4 __attribute__((ext_vector_type(4)));
typedef float f32x4 __attribute__((ext_vector_type(4)));

// fast ELU: hardware v_exp_f32; abs err ~1e-7 << 1e-3 tolerance
__device__ __forceinline__ float elu_f(float x) { return x > 0.f ? x : __expf(x) - 1.f; }
__device__ __forceinline__ float edge_score(float2 o) {
    return 1.f / (fabsf(o.x) + fabsf(o.y) + 0.001f);   // > 0 always
}

// ======================= CSR build =========================================
__global__ __launch_bounds__(256)
void k_deg(const int* __restrict__ dst, int* __restrict__ deg) {
    int e = blockIdx.x * 256 + threadIdx.x;
    if (e >= N_EDGES) return;
    atomicAdd(&deg[dst[e]], 1);
}

__global__ __launch_bounds__(256)
void k_bsum(const int* __restrict__ deg, int* __restrict__ bsum) {
    int i = blockIdx.x * 256 + threadIdx.x;
    int v = (i < N_NODES) ? deg[i] : 0;
    #pragma unroll
    for (int d = 32; d; d >>= 1) v += __shfl_xor(v, d);
    __shared__ int ws[4];
    if ((threadIdx.x & 63) == 0) ws[threadIdx.x >> 6] = v;
    __syncthreads();
    if (threadIdx.x == 0) bsum[blockIdx.x] = ws[0] + ws[1] + ws[2] + ws[3];
}

__global__ __launch_bounds__(256)
void k_bscan(const int* __restrict__ bsum, int* __restrict__ bpre, int* __restrict__ rs) {
    const int t = threadIdx.x, lane = t & 63, wv = t >> 6;
    int v = (t < NB_SCAN) ? bsum[t] : 0;
    int inc = v;
    #pragma unroll
    for (int d = 1; d < 64; d <<= 1) { int u = __shfl_up(inc, d); if (lane >= d) inc += u; }
    __shared__ int wtot[4];
    if (lane == 63) wtot[wv] = inc;
    __syncthreads();
    int add = 0;
    for (int w = 0; w < wv; ++w) add += wtot[w];
    if (t < NB_SCAN) bpre[t] = inc + add - v;
    if (t == 0) rs[N_NODES] = N_EDGES;
}

__global__ __launch_bounds__(256)
void k_wr(const int* __restrict__ deg, const int* __restrict__ bpre,
          int* __restrict__ rs, int* __restrict__ cur) {
    const int i = blockIdx.x * 256 + threadIdx.x;
    const int lane = threadIdx.x & 63, wv = threadIdx.x >> 6;
    int v = (i < N_NODES) ? deg[i] : 0;
    int inc = v;
    #pragma unroll
    for (int d = 1; d < 64; d <<= 1) { int u = __shfl_up(inc, d); if (lane >= d) inc += u; }
    __shared__ int wtot[4];
    if (lane == 63) wtot[wv] = inc;
    __syncthreads();
    int add = bpre[blockIdx.x];
    for (int w = 0; w < wv; ++w) add += wtot[w];
    if (i < N_NODES) { int excl = inc - v + add; rs[i] = excl; cur[i] = excl; }
}

// CSR fill: also emit perm (edge -> CSR slot), src_csr, score_csr so that
// downstream kernels stream in CSR order (no random reads by edge id).
__global__ __launch_bounds__(256)
void k_fill(const int* __restrict__ dst, const int* __restrict__ src,
            const float* __restrict__ off2, int* __restrict__ cur,
            int* __restrict__ perm, int* __restrict__ src_csr,
            float* __restrict__ score_csr) {
    int e = blockIdx.x * 256 + threadIdx.x;
    if (e >= N_EDGES) return;
    int p = atomicAdd(&cur[dst[e]], 1);
    perm[e] = p;
    src_csr[p] = src[e];
    score_csr[p] = edge_score(((const float2*)off2)[e]);
}

// ======================= node-weight split -> MFMA fragment layout ==========
#define WTOT 98304
__global__ __launch_bounds__(256)
void k_wsplit(const float* __restrict__ sW1, const float* __restrict__ sW2,
              const float* __restrict__ mW1, const float* __restrict__ mW2,
              const float* __restrict__ mW3, const float* __restrict__ mW4,
              _Float16* __restrict__ wsH, _Float16* __restrict__ wsL) {
    int idx = blockIdx.x * 256 + threadIdx.x;
    if (idx >= WTOT) return;
    const float* W; int base, K;
    if      (idx < 8192)  { W = sW1; base = 0;     K = 64;  }
    else if (idx < 24576) { W = sW2; base = 8192;  K = 128; }
    else if (idx < 49152) { W = mW1; base = 24576; K = 192; }
    else if (idx < 65536) { W = mW2; base = 49152; K = 128; }
    else if (idx < 81920) { W = mW3; base = 65536; K = 128; }
    else                  { W = mW4; base = 81920; K = 128; }
    int local = idx - base;
    int k = local >> 7, col = local & 127;
    int nt = col >> 4, colg = col & 15;
    int kt = k >> 5, lq = (k >> 3) & 3, i = k & 7;
    int fi = base + ((nt * (K >> 5) + kt) * 4 + lq) * 128 + colg * 8 + i;
    float w = W[k * 128 + col];
    _Float16 h = (_Float16)w;
    wsH[fi] = h;
    wsL[fi] = (_Float16)(w - (float)h);
}

// ======================= kW2 split -> A-fragment layout =====================
#define KW2TOT 8192
__global__ __launch_bounds__(256)
void k_kwsplit2(const float* __restrict__ kW2,
                _Float16* __restrict__ wkH, _Float16* __restrict__ wkL) {
    int idx = blockIdx.x * 256 + threadIdx.x;
    if (idx >= KW2TOT) return;
    int i = idx & 7, colg = (idx >> 3) & 15;
    int lq = (idx >> 7) & 3, kt = (idx >> 9) & 3, jt = idx >> 11;
    int k = kt * 32 + lq * 8 + i;
    int j = jt * 16 + colg;
    float w = kW2[k * 64 + j];
    _Float16 h = (_Float16)w;
    wkH[idx] = h;
    wkL[idx] = (_Float16)(w - (float)h);
}

// ======================= per-edge kernel-weight GEMM (no-LDS MFMA) ==========
// Same structure as r7 (validated), but: fast ELU, and epilogue scatters each
// edge's full 128B row to its CSR slot (perm[e]) so k_agg reads sequentially.
__global__ __launch_bounds__(256)
void k_kw(const float* __restrict__ off2,
          const float* __restrict__ kW1, const float* __restrict__ kb1,
          const _Float16* __restrict__ wkH, const _Float16* __restrict__ wkL,
          const float* __restrict__ kb2, const int* __restrict__ perm,
          _Float16* __restrict__ kwbuf) {
    const int t = threadIdx.x;
    const int lane = t & 63, wv = t >> 6;
    const int eb = blockIdx.x * 256 + wv * 64;
    const int colg = lane & 15, lq = lane >> 4;

    float2 o[4];
    int pidx[4];
    #pragma unroll
    for (int et = 0; et < 4; ++et) {
        o[et] = ((const float2*)off2)[eb + et * 16 + colg];
        pidx[et] = perm[eb + et * 16 + colg];
    }

    f32x4 c[4][4];   // [et][jt]
    #pragma unroll
    for (int et = 0; et < 4; ++et)
        #pragma unroll
        for (int jt = 0; jt < 4; ++jt) c[et][jt] = (f32x4){0.f, 0.f, 0.f, 0.f};

    #pragma unroll
    for (int kt = 0; kt < 4; ++kt) {
        const int k0 = kt * 32 + lq * 8;
        float4 a0 = *(const float4*)&kW1[k0];
        float4 a1 = *(const float4*)&kW1[k0 + 4];
        float4 b0 = *(const float4*)&kW1[128 + k0];
        float4 b1 = *(const float4*)&kW1[128 + k0 + 4];
        float4 c0 = *(const float4*)&kb1[k0];
        float4 c1 = *(const float4*)&kb1[k0 + 4];
        const float wa[8] = {a0.x, a0.y, a0.z, a0.w, a1.x, a1.y, a1.z, a1.w};
        const float wb[8] = {b0.x, b0.y, b0.z, b0.w, b1.x, b1.y, b1.z, b1.w};
        const float bb[8] = {c0.x, c0.y, c0.z, c0.w, c1.x, c1.y, c1.z, c1.w};

        half8 Bh[4], Bl[4];
        #pragma unroll
        for (int et = 0; et < 4; ++et) {
            #pragma unroll
            for (int i = 0; i < 8; ++i) {
                float h = elu_f(fmaf(o[et].y, wb[i], fmaf(o[et].x, wa[i], bb[i])));
                _Float16 hh = (_Float16)h;
                Bh[et][i] = hh;
                Bl[et][i] = (_Float16)(h - (float)hh);
            }
        }
        #pragma unroll
        for (int jt = 0; jt < 4; ++jt) {
            int fo = ((jt * 4 + kt) * 4 + lq) * 128 + colg * 8;
            half8 Ah = *(const half8*)&wkH[fo];
            half8 Al = *(const half8*)&wkL[fo];
            #pragma unroll
            for (int et = 0; et < 4; ++et) {
                c[et][jt] = __builtin_amdgcn_mfma_f32_16x16x32_f16(Ah, Bh[et], c[et][jt], 0, 0, 0);
                c[et][jt] = __builtin_amdgcn_mfma_f32_16x16x32_f16(Ah, Bl[et], c[et][jt], 0, 0, 0);
                c[et][jt] = __builtin_amdgcn_mfma_f32_16x16x32_f16(Al, Bh[et], c[et][jt], 0, 0, 0);
            }
        }
    }

    #pragma unroll
    for (int jt = 0; jt < 4; ++jt) {
        const int j0 = jt * 16 + lq * 4;
        float4 bv = *(const float4*)&kb2[j0];
        const float bias4[4] = {bv.x, bv.y, bv.z, bv.w};
        #pragma unroll
        for (int et = 0; et < 4; ++et) {
            half4 v;
            #pragma unroll
            for (int r = 0; r < 4; ++r) v[r] = (_Float16)(c[et][jt][r] + bias4[r]);
            *(half4*)&kwbuf[(size_t)pidx[et] * 64 + j0] = v;
        }
    }
}

// ======================= per-node softmax + gather-aggregate ================
// All inputs in CSR order: score_csr/src_csr/kwbuf stream sequentially; only
// the L2-resident 12.8MB feat table is gathered randomly.
__global__ __launch_bounds__(256)
void k_agg(const float* __restrict__ score_csr, const int* __restrict__ src_csr,
           const int* __restrict__ rs, const float* __restrict__ feat,
           const _Float16* __restrict__ kwbuf, float* __restrict__ agg) {
    const int lane = threadIdx.x & 63;
    const int wav  = threadIdx.x >> 6;
    const int gw   = blockIdx.x * 4 + wav;
    const int nw   = gridDim.x * 4;

    for (int n = gw; n < N_NODES; n += nw) {
        const int p0 = rs[n], p1 = rs[n + 1];
        if (p0 == p1) { agg[(size_t)n * 64 + lane] = 0.f; continue; }

        float mx = 0.f;
        for (int p = p0 + lane; p < p1; p += 64) mx = fmaxf(mx, score_csr[p]);
        #pragma unroll
        for (int d = 32; d; d >>= 1) mx = fmaxf(mx, __shfl_xor(mx, d));

        float sm = 0.f;
        for (int p = p0 + lane; p < p1; p += 64) sm += __expf(score_csr[p] - mx);
        #pragma unroll
        for (int d = 32; d; d >>= 1) sm += __shfl_xor(sm, d);
        const float dinv = 1.f / sm;

        float a0 = 0.f, a1 = 0.f, a2 = 0.f, a3 = 0.f;
        int p = p0;
        for (; p + 4 <= p1; p += 4) {
            float w0 = __expf(score_csr[p]     - mx) * dinv;
            float w1 = __expf(score_csr[p + 1] - mx) * dinv;
            float w2 = __expf(score_csr[p + 2] - mx) * dinv;
            float w3 = __expf(score_csr[p + 3] - mx) * dinv;
            const int s0 = src_csr[p], s1 = src_csr[p + 1];
            const int s2 = src_csr[p + 2], s3 = src_csr[p + 3];
            float f0 = feat[(size_t)s0 * 64 + lane];
            float f1 = feat[(size_t)s1 * 64 + lane];
            float f2 = feat[(size_t)s2 * 64 + lane];
            float f3 = feat[(size_t)s3 * 64 + lane];
            float k0 = (float)kwbuf[(size_t)(p)     * 64 + lane];
            float k1 = (float)kwbuf[(size_t)(p + 1) * 64 + lane];
            float k2 = (float)kwbuf[(size_t)(p + 2) * 64 + lane];
            float k3 = (float)kwbuf[(size_t)(p + 3) * 64 + lane];
            a0 = fmaf(f0 * w0, k0, a0);
            a1 = fmaf(f1 * w1, k1, a1);
            a2 = fmaf(f2 * w2, k2, a2);
            a3 = fmaf(f3 * w3, k3, a3);
        }
        for (; p < p1; ++p) {
            float wgt = __expf(score_csr[p] - mx) * dinv;
            float f = feat[(size_t)src_csr[p] * 64 + lane];
            float kv = (float)kwbuf[(size_t)p * 64 + lane];
            a0 = fmaf(f * wgt, kv, a0);
        }
        agg[(size_t)n * 64 + lane] = (a0 + a1) + (a2 + a3);
    }
}

// ======================= fused node pipeline (MFMA) =========================
__device__ __forceinline__
void mm64(const char* XH, const char* XL, const _Float16* __restrict__ WH,
          const _Float16* __restrict__ WL, int K, int lane, int wv, f32x4 c[4][2]) {
    const int colg = lane & 15, lq = lane >> 4;
    #pragma unroll
    for (int m = 0; m < 4; ++m)
        #pragma unroll
        for (int j = 0; j < 2; ++j) c[m][j] = (f32x4){0.f, 0.f, 0.f, 0.f};
    const int KT = K >> 5;
    for (int kt = 0; kt < KT; ++kt) {
        half8 Bh[2], Bl[2], Ah[4], Al[4];
        #pragma unroll
        for (int j = 0; j < 2; ++j) {
            int fo = ((((wv * 2 + j) * KT + kt) * 4 + lq) * 128) + colg * 8;
            Bh[j] = *(const half8*)&WH[fo];
            Bl[j] = *(const half8*)&WL[fo];
        }
        #pragma unroll
        for (int m = 0; m < 4; ++m) {
            int row = m * 16 + colg;
            int byte = ((row * K + kt * 32 + lq * 8) * 2) ^ ((row & 7) << 4);
            Ah[m] = *(const half8*)(XH + byte);
            Al[m] = *(const half8*)(XL + byte);
        }
        #pragma unroll
        for (int m = 0; m < 4; ++m)
            #pragma unroll
            for (int j = 0; j < 2; ++j) {
                c[m][j] = __builtin_amdgcn_mfma_f32_16x16x32_f16(Ah[m], Bh[j], c[m][j], 0, 0, 0);
                c[m][j] = __builtin_amdgcn_mfma_f32_16x16x32_f16(Ah[m], Bl[j], c[m][j], 0, 0, 0);
                c[m][j] = __builtin_amdgcn_mfma_f32_16x16x32_f16(Al[m], Bh[j], c[m][j], 0, 0, 0);
            }
    }
}

__device__ __forceinline__
void epi_lds(char* XH, char* XL, int Knext, int colOff, int lane, int wv,
             f32x4 c[4][2], const float* __restrict__ bias, bool do_elu) {
    const int colg = lane & 15, lq = lane >> 4;
    float bj[2] = { bias[wv * 32 + colg], bias[wv * 32 + 16 + colg] };
    #pragma unroll
    for (int m = 0; m < 4; ++m)
        #pragma unroll
        for (int j = 0; j < 2; ++j) {
            int col = colOff + wv * 32 + j * 16 + colg;
            #pragma unroll
            for (int r = 0; r < 4; ++r) {
                int row = m * 16 + lq * 4 + r;
                float v = c[m][j][r] + bj[j];
                if (do_elu) v = elu_f(v);
                _Float16 h = (_Float16)v;
                int byte = ((row * Knext + col) * 2) ^ ((row & 7) << 4);
                *(_Float16*)(XH + byte) = h;
                *(_Float16*)(XL + byte) = (_Float16)(v - (float)h);
            }
        }
}

__global__ __launch_bounds__(256)
void k_node(const float* __restrict__ feat, const float* __restrict__ agg,
            const _Float16* __restrict__ wsH, const _Float16* __restrict__ wsL,
            const float* __restrict__ sb1, const float* __restrict__ sb2,
            const float* __restrict__ mb1, const float* __restrict__ mb2,
            const float* __restrict__ mb3, const float* __restrict__ mb4,
            float* __restrict__ out) {
    __shared__ _Float16 XH[64 * 192];
    __shared__ _Float16 XL[64 * 192];
    const int t = threadIdx.x;
    const int lane = t & 63, wv = t >> 6;
    const int row0 = blockIdx.x * 64;
    f32x4 c[4][2];

    {
        int r = t >> 2, c4 = (t & 3) * 4;
        #pragma unroll
        for (int q = 0; q < 4; ++q) {
            int col = (c4 + q) * 4;
            float4 v = make_float4(0.f, 0.f, 0.f, 0.f);
            if (row0 + r < N_NODES) v = *(const float4*)&feat[(size_t)(row0 + r) * 64 + col];
            _Float16 h4h[4], h4l[4];
            float vv[4] = {v.x, v.y, v.z, v.w};
            #pragma unroll
            for (int i = 0; i < 4; ++i) {
                _Float16 h = (_Float16)vv[i];
                h4h[i] = h; h4l[i] = (_Float16)(vv[i] - (float)h);
            }
            int byte = ((r * 64 + col) * 2) ^ ((r & 7) << 4);
            *(ulong1*)((char*)XH + byte) = *(ulong1*)h4h;
            *(ulong1*)((char*)XL + byte) = *(ulong1*)h4l;
        }
    }
    __syncthreads();

    mm64((const char*)XH, (const char*)XL, wsH + 0, wsL + 0, 64, lane, wv, c);
    __syncthreads();
    epi_lds((char*)XH, (char*)XL, 128, 0, lane, wv, c, sb1, true);
    __syncthreads();

    mm64((const char*)XH, (const char*)XL, wsH + 8192, wsL + 8192, 128, lane, wv, c);
    __syncthreads();
    epi_lds((char*)XH, (char*)XL, 192, 64, lane, wv, c, sb2, false);
    {
        int r = t >> 2, c4 = (t & 3) * 4;
        #pragma unroll
        for (int q = 0; q < 4; ++q) {
            int col = (c4 + q) * 4;
            float4 v = make_float4(0.f, 0.f, 0.f, 0.f);
            if (row0 + r < N_NODES) v = *(const float4*)&agg[(size_t)(row0 + r) * 64 + col];
            _Float16 h4h[4], h4l[4];
            float vv[4] = {v.x, v.y, v.z, v.w};
            #pragma unroll
            for (int i = 0; i < 4; ++i) {
                _Float16 h = (_Float16)vv[i];
                h4h[i] = h; h4l[i] = (_Float16)(vv[i] - (float)h);
            }
            int byte = ((r * 192 + col) * 2) ^ ((r & 7) << 4);
            *(ulong1*)((char*)XH + byte) = *(ulong1*)h4h;
            *(ulong1*)((char*)XL + byte) = *(ulong1*)h4l;
        }
    }
    __syncthreads();

    mm64((const char*)XH, (const char*)XL, wsH + 24576, wsL + 24576, 192, lane, wv, c);
    __syncthreads();
    epi_lds((char*)XH, (char*)XL, 128, 0, lane, wv, c, mb1, true);
    __syncthreads();

    mm64((const char*)XH, (const char*)XL, wsH + 49152, wsL + 49152, 128, lane, wv, c);
    __syncthreads();
    epi_lds((char*)XH, (char*)XL, 128, 0, lane, wv, c, mb2, true);
    __syncthreads();

    mm64((const char*)XH, (const char*)XL, wsH + 65536, wsL + 65536, 128, lane, wv, c);
    __syncthreads();
    epi_lds((char*)XH, (char*)XL, 128, 0, lane, wv, c, mb3, true);
    __syncthreads();

    mm64((const char*)XH, (const char*)XL, wsH + 81920, wsL + 81920, 128, lane, wv, c);
    {
        const int colg = lane & 15, lq = lane >> 4;
        float bj[2] = { mb4[wv * 32 + colg], mb4[wv * 32 + 16 + colg] };
        #pragma unroll
        for (int m = 0; m < 4; ++m)
            #pragma unroll
            for (int j = 0; j < 2; ++j) {
                int col = wv * 32 + j * 16 + colg;
                #pragma unroll
                for (int r = 0; r < 4; ++r) {
                    int row = row0 + m * 16 + lq * 4 + r;
                    if (row < N_NODES)
                        out[(size_t)row * 128 + col] = c[m][j][r] + bj[j];
                }
            }
    }
}

// ============================================================================
extern "C" void kernel_launch(void* const* d_in, const int* in_sizes, int n_in,
                              void* d_out, int out_size, void* d_ws, size_t ws_size,
                              hipStream_t stream) {
    (void)in_sizes; (void)n_in; (void)out_size; (void)ws_size;
    const float* feat = (const float*)d_in[0];
    const float* off2 = (const float*)d_in[1];
    const int*   src  = (const int*)d_in[2];
    const int*   dst  = (const int*)d_in[3];
    const float* kW1  = (const float*)d_in[4];
    const float* kb1  = (const float*)d_in[5];
    const float* kW2  = (const float*)d_in[6];
    const float* kb2  = (const float*)d_in[7];
    const float* sW1  = (const float*)d_in[8];
    const float* sb1  = (const float*)d_in[9];
    const float* sW2  = (const float*)d_in[10];
    const float* sb2  = (const float*)d_in[11];
    const float* mW1  = (const float*)d_in[12];
    const float* mb1  = (const float*)d_in[13];
    const float* mW2  = (const float*)d_in[14];
    const float* mb2  = (const float*)d_in[15];
    const float* mW3  = (const float*)d_in[16];
    const float* mb3  = (const float*)d_in[17];
    const float* mW4  = (const float*)d_in[18];
    const float* mb4  = (const float*)d_in[19];

    char* ws = (char*)d_ws;
    size_t off = 0;
    auto alloc = [&](size_t bytes) -> void* {
        void* p = ws + off;
        off += (bytes + 255) & ~(size_t)255;
        return p;
    };
    int*   deg    = (int*)alloc((size_t)N_NODES * 4);
    int*   rs     = (int*)alloc((size_t)(N_NODES + 8) * 4);
    int*   cur    = (int*)alloc((size_t)N_NODES * 4);
    int*   bsum   = (int*)alloc((size_t)NB_SCAN * 4);
    int*   bpre   = (int*)alloc((size_t)NB_SCAN * 4);
    int*   perm   = (int*)alloc((size_t)N_EDGES * 4);
    int*   srcc   = (int*)alloc((size_t)N_EDGES * 4);
    float* scorec = (float*)alloc((size_t)N_EDGES * 4);
    float* agg    = (float*)alloc((size_t)N_NODES * 64 * 4);
    _Float16* wsH = (_Float16*)alloc((size_t)WTOT * 2);
    _Float16* wsL = (_Float16*)alloc((size_t)WTOT * 2);
    _Float16* wkH = (_Float16*)alloc((size_t)KW2TOT * 2);
    _Float16* wkL = (_Float16*)alloc((size_t)KW2TOT * 2);
    _Float16* kwbuf = (_Float16*)alloc((size_t)N_EDGES * 64 * 2);

    hipMemsetAsync(deg, 0, (size_t)N_NODES * 4, stream);

    const int EB = (N_EDGES + 255) / 256;   // 3125
    const int GB = (N_NODES + 63) / 64;     // 782

    k_deg     <<<EB, 256, 0, stream>>>(dst, deg);
    k_bsum    <<<NB_SCAN, 256, 0, stream>>>(deg, bsum);
    k_bscan   <<<1, 256, 0, stream>>>(bsum, bpre, rs);
    k_wr      <<<NB_SCAN, 256, 0, stream>>>(deg, bpre, rs, cur);
    k_fill    <<<EB, 256, 0, stream>>>(dst, src, off2, cur, perm, srcc, scorec);
    k_wsplit  <<<(WTOT + 255) / 256, 256, 0, stream>>>(sW1, sW2, mW1, mW2, mW3, mW4, wsH, wsL);
    k_kwsplit2<<<(KW2TOT + 255) / 256, 256, 0, stream>>>(kW2, wkH, wkL);

    k_kw <<<N_EDGES / 256, 256, 0, stream>>>(off2, kW1, kb1, wkH, wkL, kb2, perm, kwbuf);
    k_agg<<<2048, 256, 0, stream>>>(scorec, srcc, rs, feat, kwbuf, agg);

    k_node<<<GB, 256, 0, stream>>>(feat, agg, wsH, wsL, sb1, sb2, mb1, mb2, mb3, mb4,
                                   (float*)d_out);
}

// Round 9
// 278.398 us; speedup vs baseline: 4.2745x; 1.0017x over previous
//
#include <hip/hip_runtime.h>
#include <hip/hip_bf16.h>
#include <math.h>

#define N_NODES 50000
#define N_EDGES 800000
#define NB_SCAN ((N_NODES + 255) / 256)   // 196

typedef _Float16 half8 __attribute__((ext_vector_type(8)));
typedef _Float16 half4 __attribute__((ext_vector_type(4)));
typedef float f32x4 __attribute__((ext_vector_type(4)));

// fast ELU: hardware v_exp_f32; abs err ~1e-7 << tolerance
__device__ __forceinline__ float elu_f(float x) { return x > 0.f ? x : __expf(x) - 1.f; }
__device__ __forceinline__ float edge_score(float2 o) {
    return 1.f / (fabsf(o.x) + fabsf(o.y) + 0.001f);   // > 0 always
}

// ======================= CSR build =========================================
__global__ __launch_bounds__(256)
void k_deg(const int* __restrict__ dst, int* __restrict__ deg) {
    int e = blockIdx.x * 256 + threadIdx.x;
    if (e >= N_EDGES) return;
    atomicAdd(&deg[dst[e]], 1);
}

__global__ __launch_bounds__(256)
void k_bsum(const int* __restrict__ deg, int* __restrict__ bsum) {
    int i = blockIdx.x * 256 + threadIdx.x;
    int v = (i < N_NODES) ? deg[i] : 0;
    #pragma unroll
    for (int d = 32; d; d >>= 1) v += __shfl_xor(v, d);
    __shared__ int ws[4];
    if ((threadIdx.x & 63) == 0) ws[threadIdx.x >> 6] = v;
    __syncthreads();
    if (threadIdx.x == 0) bsum[blockIdx.x] = ws[0] + ws[1] + ws[2] + ws[3];
}

__global__ __launch_bounds__(256)
void k_bscan(const int* __restrict__ bsum, int* __restrict__ bpre, int* __restrict__ rs) {
    const int t = threadIdx.x, lane = t & 63, wv = t >> 6;
    int v = (t < NB_SCAN) ? bsum[t] : 0;
    int inc = v;
    #pragma unroll
    for (int d = 1; d < 64; d <<= 1) { int u = __shfl_up(inc, d); if (lane >= d) inc += u; }
    __shared__ int wtot[4];
    if (lane == 63) wtot[wv] = inc;
    __syncthreads();
    int add = 0;
    for (int w = 0; w < wv; ++w) add += wtot[w];
    if (t < NB_SCAN) bpre[t] = inc + add - v;
    if (t == 0) rs[N_NODES] = N_EDGES;
}

__global__ __launch_bounds__(256)
void k_wr(const int* __restrict__ deg, const int* __restrict__ bpre,
          int* __restrict__ rs, int* __restrict__ cur) {
    const int i = blockIdx.x * 256 + threadIdx.x;
    const int lane = threadIdx.x & 63, wv = threadIdx.x >> 6;
    int v = (i < N_NODES) ? deg[i] : 0;
    int inc = v;
    #pragma unroll
    for (int d = 1; d < 64; d <<= 1) { int u = __shfl_up(inc, d); if (lane >= d) inc += u; }
    __shared__ int wtot[4];
    if (lane == 63) wtot[wv] = inc;
    __syncthreads();
    int add = bpre[blockIdx.x];
    for (int w = 0; w < wv; ++w) add += wtot[w];
    if (i < N_NODES) { int excl = inc - v + add; rs[i] = excl; cur[i] = excl; }
}

// CSR fill: emit eid_csr (slot -> edge), src_csr, score_csr.
__global__ __launch_bounds__(256)
void k_fill(const int* __restrict__ dst, const int* __restrict__ src,
            const float* __restrict__ off2, int* __restrict__ cur,
            int* __restrict__ eid_csr, int* __restrict__ src_csr,
            float* __restrict__ score_csr) {
    int e = blockIdx.x * 256 + threadIdx.x;
    if (e >= N_EDGES) return;
    int p = atomicAdd(&cur[dst[e]], 1);
    eid_csr[p] = e;
    src_csr[p] = src[e];
    score_csr[p] = edge_score(((const float2*)off2)[e]);
}

// ======================= weight split (node MLP + kW2) — one kernel =========
// node: L0 sW1 K=64 @0 | L1 sW2 K=128 @8192 | L2 mW1 K=192 @24576
//       L3 mW2 K=128 @49152 | L4 mW3 K=128 @65536 | L5 mW4 K=128 @81920
#define WTOT 98304
#define KW2TOT 8192
__global__ __launch_bounds__(256)
void k_wsplit(const float* __restrict__ sW1, const float* __restrict__ sW2,
              const float* __restrict__ mW1, const float* __restrict__ mW2,
              const float* __restrict__ mW3, const float* __restrict__ mW4,
              const float* __restrict__ kW2,
              _Float16* __restrict__ wsH, _Float16* __restrict__ wsL,
              _Float16* __restrict__ wkH, _Float16* __restrict__ wkL) {
    int idx = blockIdx.x * 256 + threadIdx.x;
    if (idx < WTOT) {
        const float* W; int base, K;
        if      (idx < 8192)  { W = sW1; base = 0;     K = 64;  }
        else if (idx < 24576) { W = sW2; base = 8192;  K = 128; }
        else if (idx < 49152) { W = mW1; base = 24576; K = 192; }
        else if (idx < 65536) { W = mW2; base = 49152; K = 128; }
        else if (idx < 81920) { W = mW3; base = 65536; K = 128; }
        else                  { W = mW4; base = 81920; K = 128; }
        int local = idx - base;
        int k = local >> 7, col = local & 127;
        int nt = col >> 4, colg = col & 15;
        int kt = k >> 5, lq = (k >> 3) & 3, i = k & 7;
        int fi = base + ((nt * (K >> 5) + kt) * 4 + lq) * 128 + colg * 8 + i;
        float w = W[k * 128 + col];
        _Float16 h = (_Float16)w;
        wsH[fi] = h;
        wsL[fi] = (_Float16)(w - (float)h);
    } else if (idx < WTOT + KW2TOT) {
        int x = idx - WTOT;
        int i = x & 7, colg = (x >> 3) & 15;
        int lq = (x >> 7) & 3, kt = (x >> 9) & 3, jt = x >> 11;
        int k = kt * 32 + lq * 8 + i;
        int j = jt * 16 + colg;
        float w = kW2[k * 64 + j];
        _Float16 h = (_Float16)w;
        wkH[x] = h;
        wkL[x] = (_Float16)(w - (float)h);
    }
}

// ======================= per-edge kernel-weight GEMM (CSR-ordered) ==========
// Wave owns 64 consecutive CSR slots. Gathers off2 via eid_csr (L2-resident,
// random 8B); writes kwbuf SEQUENTIALLY (contiguous 8KB per wave).
__global__ __launch_bounds__(256)
void k_kw(const float* __restrict__ off2, const int* __restrict__ eid_csr,
          const float* __restrict__ kW1, const float* __restrict__ kb1,
          const _Float16* __restrict__ wkH, const _Float16* __restrict__ wkL,
          const float* __restrict__ kb2, _Float16* __restrict__ kwbuf) {
    const int t = threadIdx.x;
    const int lane = t & 63, wv = t >> 6;
    const int pb = blockIdx.x * 256 + wv * 64;   // CSR slot base for this wave
    const int colg = lane & 15, lq = lane >> 4;

    float2 o[4];
    #pragma unroll
    for (int et = 0; et < 4; ++et)
        o[et] = ((const float2*)off2)[eid_csr[pb + et * 16 + colg]];

    f32x4 c[4][4];   // [et][jt]
    #pragma unroll
    for (int et = 0; et < 4; ++et)
        #pragma unroll
        for (int jt = 0; jt < 4; ++jt) c[et][jt] = (f32x4){0.f, 0.f, 0.f, 0.f};

    #pragma unroll
    for (int kt = 0; kt < 4; ++kt) {
        const int k0 = kt * 32 + lq * 8;
        float4 a0 = *(const float4*)&kW1[k0];
        float4 a1 = *(const float4*)&kW1[k0 + 4];
        float4 b0 = *(const float4*)&kW1[128 + k0];
        float4 b1 = *(const float4*)&kW1[128 + k0 + 4];
        float4 c0 = *(const float4*)&kb1[k0];
        float4 c1 = *(const float4*)&kb1[k0 + 4];
        const float wa[8] = {a0.x, a0.y, a0.z, a0.w, a1.x, a1.y, a1.z, a1.w};
        const float wb[8] = {b0.x, b0.y, b0.z, b0.w, b1.x, b1.y, b1.z, b1.w};
        const float bb[8] = {c0.x, c0.y, c0.z, c0.w, c1.x, c1.y, c1.z, c1.w};

        half8 Bh[4], Bl[4];
        #pragma unroll
        for (int et = 0; et < 4; ++et) {
            #pragma unroll
            for (int i = 0; i < 8; ++i) {
                float h = elu_f(fmaf(o[et].y, wb[i], fmaf(o[et].x, wa[i], bb[i])));
                _Float16 hh = (_Float16)h;
                Bh[et][i] = hh;
                Bl[et][i] = (_Float16)(h - (float)hh);
            }
        }
        #pragma unroll
        for (int jt = 0; jt < 4; ++jt) {
            int fo = ((jt * 4 + kt) * 4 + lq) * 128 + colg * 8;
            half8 Ah = *(const half8*)&wkH[fo];
            half8 Al = *(const half8*)&wkL[fo];
            #pragma unroll
            for (int et = 0; et < 4; ++et) {
                c[et][jt] = __builtin_amdgcn_mfma_f32_16x16x32_f16(Ah, Bh[et], c[et][jt], 0, 0, 0);
                c[et][jt] = __builtin_amdgcn_mfma_f32_16x16x32_f16(Ah, Bl[et], c[et][jt], 0, 0, 0);
                c[et][jt] = __builtin_amdgcn_mfma_f32_16x16x32_f16(Al, Bh[et], c[et][jt], 0, 0, 0);
            }
        }
    }

    // epilogue: slot p = pb + et*16+colg (sequential rows), 8B stores
    #pragma unroll
    for (int jt = 0; jt < 4; ++jt) {
        const int j0 = jt * 16 + lq * 4;
        float4 bv = *(const float4*)&kb2[j0];
        const float bias4[4] = {bv.x, bv.y, bv.z, bv.w};
        #pragma unroll
        for (int et = 0; et < 4; ++et) {
            const int p = pb + et * 16 + colg;
            half4 v;
            #pragma unroll
            for (int r = 0; r < 4; ++r) v[r] = (_Float16)(c[et][jt][r] + bias4[r]);
            *(half4*)&kwbuf[(size_t)p * 64 + j0] = v;
        }
    }
}

// ======================= per-node softmax + gather-aggregate ================
__global__ __launch_bounds__(256)
void k_agg(const float* __restrict__ score_csr, const int* __restrict__ src_csr,
           const int* __restrict__ rs, const float* __restrict__ feat,
           const _Float16* __restrict__ kwbuf, float* __restrict__ agg) {
    const int lane = threadIdx.x & 63;
    const int wav  = threadIdx.x >> 6;
    const int gw   = blockIdx.x * 4 + wav;
    const int nw   = gridDim.x * 4;

    for (int n = gw; n < N_NODES; n += nw) {
        const int p0 = rs[n], p1 = rs[n + 1];
        if (p0 == p1) { agg[(size_t)n * 64 + lane] = 0.f; continue; }

        float mx = 0.f;
        for (int p = p0 + lane; p < p1; p += 64) mx = fmaxf(mx, score_csr[p]);
        #pragma unroll
        for (int d = 32; d; d >>= 1) mx = fmaxf(mx, __shfl_xor(mx, d));

        float sm = 0.f;
        for (int p = p0 + lane; p < p1; p += 64) sm += __expf(score_csr[p] - mx);
        #pragma unroll
        for (int d = 32; d; d >>= 1) sm += __shfl_xor(sm, d);
        const float dinv = 1.f / sm;

        float a0 = 0.f, a1 = 0.f, a2 = 0.f, a3 = 0.f;
        int p = p0;
        for (; p + 4 <= p1; p += 4) {
            float w0 = __expf(score_csr[p]     - mx) * dinv;
            float w1 = __expf(score_csr[p + 1] - mx) * dinv;
            float w2 = __expf(score_csr[p + 2] - mx) * dinv;
            float w3 = __expf(score_csr[p + 3] - mx) * dinv;
            const int s0 = src_csr[p], s1 = src_csr[p + 1];
            const int s2 = src_csr[p + 2], s3 = src_csr[p + 3];
            float f0 = feat[(size_t)s0 * 64 + lane];
            float f1 = feat[(size_t)s1 * 64 + lane];
            float f2 = feat[(size_t)s2 * 64 + lane];
            float f3 = feat[(size_t)s3 * 64 + lane];
            float k0 = (float)kwbuf[(size_t)(p)     * 64 + lane];
            float k1 = (float)kwbuf[(size_t)(p + 1) * 64 + lane];
            float k2 = (float)kwbuf[(size_t)(p + 2) * 64 + lane];
            float k3 = (float)kwbuf[(size_t)(p + 3) * 64 + lane];
            a0 = fmaf(f0 * w0, k0, a0);
            a1 = fmaf(f1 * w1, k1, a1);
            a2 = fmaf(f2 * w2, k2, a2);
            a3 = fmaf(f3 * w3, k3, a3);
        }
        for (; p < p1; ++p) {
            float wgt = __expf(score_csr[p] - mx) * dinv;
            float f = feat[(size_t)src_csr[p] * 64 + lane];
            float kv = (float)kwbuf[(size_t)p * 64 + lane];
            a0 = fmaf(f * wgt, kv, a0);
        }
        agg[(size_t)n * 64 + lane] = (a0 + a1) + (a2 + a3);
    }
}

// ======================= fused node pipeline (MFMA) =========================
// X LDS is 64x128 hi/lo (32 KB total -> 5 blocks/CU). agg for head-L1 is
// staged directly into A-fragment REGISTERS (16 half8), not LDS.
__device__ __forceinline__
void mm64(const char* XH, const char* XL, const _Float16* __restrict__ WH,
          const _Float16* __restrict__ WL, int K, int lane, int wv, f32x4 c[4][2]) {
    const int colg = lane & 15, lq = lane >> 4;
    #pragma unroll
    for (int m = 0; m < 4; ++m)
        #pragma unroll
        for (int j = 0; j < 2; ++j) c[m][j] = (f32x4){0.f, 0.f, 0.f, 0.f};
    const int KT = K >> 5;
    for (int kt = 0; kt < KT; ++kt) {
        half8 Bh[2], Bl[2], Ah[4], Al[4];
        #pragma unroll
        for (int j = 0; j < 2; ++j) {
            int fo = ((((wv * 2 + j) * KT + kt) * 4 + lq) * 128) + colg * 8;
            Bh[j] = *(const half8*)&WH[fo];
            Bl[j] = *(const half8*)&WL[fo];
        }
        #pragma unroll
        for (int m = 0; m < 4; ++m) {
            int row = m * 16 + colg;
            int byte = ((row * K + kt * 32 + lq * 8) * 2) ^ ((row & 7) << 4);
            Ah[m] = *(const half8*)(XH + byte);
            Al[m] = *(const half8*)(XL + byte);
        }
        #pragma unroll
        for (int m = 0; m < 4; ++m)
            #pragma unroll
            for (int j = 0; j < 2; ++j) {
                c[m][j] = __builtin_amdgcn_mfma_f32_16x16x32_f16(Ah[m], Bh[j], c[m][j], 0, 0, 0);
                c[m][j] = __builtin_amdgcn_mfma_f32_16x16x32_f16(Ah[m], Bl[j], c[m][j], 0, 0, 0);
                c[m][j] = __builtin_amdgcn_mfma_f32_16x16x32_f16(Al[m], Bh[j], c[m][j], 0, 0, 0);
            }
    }
}

// head-L1: K=192; kt 0,1 (agg) come from registers, kt 2..5 (selfb) from LDS
// (selfb stored as its own K=128 swizzled layout).
__device__ __forceinline__
void mm64_h1(const half8 aggH[4][2], const half8 aggL[4][2],
             const char* XH, const char* XL,
             const _Float16* __restrict__ WH, const _Float16* __restrict__ WL,
             int lane, int wv, f32x4 c[4][2]) {
    const int colg = lane & 15, lq = lane >> 4;
    #pragma unroll
    for (int m = 0; m < 4; ++m)
        #pragma unroll
        for (int j = 0; j < 2; ++j) c[m][j] = (f32x4){0.f, 0.f, 0.f, 0.f};
    #pragma unroll
    for (int kt = 0; kt < 6; ++kt) {
        half8 Bh[2], Bl[2], Ah[4], Al[4];
        #pragma unroll
        for (int j = 0; j < 2; ++j) {
            int fo = ((((wv * 2 + j) * 6 + kt) * 4 + lq) * 128) + colg * 8;
            Bh[j] = *(const half8*)&WH[fo];
            Bl[j] = *(const half8*)&WL[fo];
        }
        if (kt < 2) {
            #pragma unroll
            for (int m = 0; m < 4; ++m) { Ah[m] = aggH[m][kt]; Al[m] = aggL[m][kt]; }
        } else {
            #pragma unroll
            for (int m = 0; m < 4; ++m) {
                int row = m * 16 + colg;
                int byte = ((row * 128 + (kt - 2) * 32 + lq * 8) * 2) ^ ((row & 7) << 4);
                Ah[m] = *(const half8*)(XH + byte);
                Al[m] = *(const half8*)(XL + byte);
            }
        }
        #pragma unroll
        for (int m = 0; m < 4; ++m)
            #pragma unroll
            for (int j = 0; j < 2; ++j) {
                c[m][j] = __builtin_amdgcn_mfma_f32_16x16x32_f16(Ah[m], Bh[j], c[m][j], 0, 0, 0);
                c[m][j] = __builtin_amdgcn_mfma_f32_16x16x32_f16(Ah[m], Bl[j], c[m][j], 0, 0, 0);
                c[m][j] = __builtin_amdgcn_mfma_f32_16x16x32_f16(Al[m], Bh[j], c[m][j], 0, 0, 0);
            }
    }
}

__device__ __forceinline__
void epi_lds(char* XH, char* XL, int lane, int wv,
             f32x4 c[4][2], const float* __restrict__ bias, bool do_elu) {
    const int colg = lane & 15, lq = lane >> 4;
    float bj[2] = { bias[wv * 32 + colg], bias[wv * 32 + 16 + colg] };
    #pragma unroll
    for (int m = 0; m < 4; ++m)
        #pragma unroll
        for (int j = 0; j < 2; ++j) {
            int col = wv * 32 + j * 16 + colg;
            #pragma unroll
            for (int r = 0; r < 4; ++r) {
                int row = m * 16 + lq * 4 + r;
                float v = c[m][j][r] + bj[j];
                if (do_elu) v = elu_f(v);
                _Float16 h = (_Float16)v;
                int byte = ((row * 128 + col) * 2) ^ ((row & 7) << 4);
                *(_Float16*)(XH + byte) = h;
                *(_Float16*)(XL + byte) = (_Float16)(v - (float)h);
            }
        }
}

__global__ __launch_bounds__(256)
void k_node(const float* __restrict__ feat, const float* __restrict__ agg,
            const _Float16* __restrict__ wsH, const _Float16* __restrict__ wsL,
            const float* __restrict__ sb1, const float* __restrict__ sb2,
            const float* __restrict__ mb1, const float* __restrict__ mb2,
            const float* __restrict__ mb3, const float* __restrict__ mb4,
            float* __restrict__ out) {
    __shared__ _Float16 XH[64 * 128];   // 16 KB
    __shared__ _Float16 XL[64 * 128];   // 16 KB
    const int t = threadIdx.x;
    const int lane = t & 63, wv = t >> 6;
    const int colg = lane & 15, lq = lane >> 4;
    const int row0 = blockIdx.x * 64;
    f32x4 c[4][2];

    // ---- stage feat[64][64] -> X (K=64 swizzled layout in front half) ----
    {
        int r = t >> 2, c4 = (t & 3) * 4;
        #pragma unroll
        for (int q = 0; q < 4; ++q) {
            int col = (c4 + q) * 4;
            float4 v = make_float4(0.f, 0.f, 0.f, 0.f);
            if (row0 + r < N_NODES) v = *(const float4*)&feat[(size_t)(row0 + r) * 64 + col];
            _Float16 h4h[4], h4l[4];
            float vv[4] = {v.x, v.y, v.z, v.w};
            #pragma unroll
            for (int i = 0; i < 4; ++i) {
                _Float16 h = (_Float16)vv[i];
                h4h[i] = h; h4l[i] = (_Float16)(vv[i] - (float)h);
            }
            int byte = ((r * 64 + col) * 2) ^ ((r & 7) << 4);
            *(ulong1*)((char*)XH + byte) = *(ulong1*)h4h;
            *(ulong1*)((char*)XL + byte) = *(ulong1*)h4l;
        }
    }
    __syncthreads();

    // ---- self L1: K=64, ELU ----
    mm64((const char*)XH, (const char*)XL, wsH + 0, wsL + 0, 64, lane, wv, c);
    __syncthreads();
    epi_lds((char*)XH, (char*)XL, lane, wv, c, sb1, true);
    __syncthreads();

    // ---- self L2: K=128, no ELU -> selfb stays in X (K=128 layout) ----
    mm64((const char*)XH, (const char*)XL, wsH + 8192, wsL + 8192, 128, lane, wv, c);

    // ---- stage agg -> head-L1 A-fragment registers (16 half8 = 32 VGPR) ----
    half8 aggH[4][2], aggL[4][2];
    #pragma unroll
    for (int m = 0; m < 4; ++m) {
        int row = row0 + m * 16 + colg;
        #pragma unroll
        for (int kt = 0; kt < 2; ++kt) {
            int k0 = kt * 32 + lq * 8;
            float4 v0 = make_float4(0.f, 0.f, 0.f, 0.f), v1 = v0;
            if (row < N_NODES) {
                v0 = *(const float4*)&agg[(size_t)row * 64 + k0];
                v1 = *(const float4*)&agg[(size_t)row * 64 + k0 + 4];
            }
            float vv[8] = {v0.x, v0.y, v0.z, v0.w, v1.x, v1.y, v1.z, v1.w};
            #pragma unroll
            for (int i = 0; i < 8; ++i) {
                _Float16 h = (_Float16)vv[i];
                aggH[m][kt][i] = h;
                aggL[m][kt][i] = (_Float16)(vv[i] - (float)h);
            }
        }
    }
    __syncthreads();
    epi_lds((char*)XH, (char*)XL, lane, wv, c, sb2, false);
    __syncthreads();

    // ---- head L1: K=192 (regs + LDS), ELU ----
    mm64_h1(aggH, aggL, (const char*)XH, (const char*)XL,
            wsH + 24576, wsL + 24576, lane, wv, c);
    __syncthreads();
    epi_lds((char*)XH, (char*)XL, lane, wv, c, mb1, true);
    __syncthreads();

    // ---- head L2: K=128, ELU ----
    mm64((const char*)XH, (const char*)XL, wsH + 49152, wsL + 49152, 128, lane, wv, c);
    __syncthreads();
    epi_lds((char*)XH, (char*)XL, lane, wv, c, mb2, true);
    __syncthreads();

    // ---- head L3: K=128, ELU ----
    mm64((const char*)XH, (const char*)XL, wsH + 65536, wsL + 65536, 128, lane, wv, c);
    __syncthreads();
    epi_lds((char*)XH, (char*)XL, lane, wv, c, mb3, true);
    __syncthreads();

    // ---- head L4: K=128 -> global out ----
    mm64((const char*)XH, (const char*)XL, wsH + 81920, wsL + 81920, 128, lane, wv, c);
    {
        float bj[2] = { mb4[wv * 32 + colg], mb4[wv * 32 + 16 + colg] };
        #pragma unroll
        for (int m = 0; m < 4; ++m)
            #pragma unroll
            for (int j = 0; j < 2; ++j) {
                int col = wv * 32 + j * 16 + colg;
                #pragma unroll
                for (int r = 0; r < 4; ++r) {
                    int row = row0 + m * 16 + lq * 4 + r;
                    if (row < N_NODES)
                        out[(size_t)row * 128 + col] = c[m][j][r] + bj[j];
                }
            }
    }
}

// ============================================================================
extern "C" void kernel_launch(void* const* d_in, const int* in_sizes, int n_in,
                              void* d_out, int out_size, void* d_ws, size_t ws_size,
                              hipStream_t stream) {
    (void)in_sizes; (void)n_in; (void)out_size; (void)ws_size;
    const float* feat = (const float*)d_in[0];
    const float* off2 = (const float*)d_in[1];
    const int*   src  = (const int*)d_in[2];
    const int*   dst  = (const int*)d_in[3];
    const float* kW1  = (const float*)d_in[4];
    const float* kb1  = (const float*)d_in[5];
    const float* kW2  = (const float*)d_in[6];
    const float* kb2  = (const float*)d_in[7];
    const float* sW1  = (const float*)d_in[8];
    const float* sb1  = (const float*)d_in[9];
    const float* sW2  = (const float*)d_in[10];
    const float* sb2  = (const float*)d_in[11];
    const float* mW1  = (const float*)d_in[12];
    const float* mb1  = (const float*)d_in[13];
    const float* mW2  = (const float*)d_in[14];
    const float* mb2  = (const float*)d_in[15];
    const float* mW3  = (const float*)d_in[16];
    const float* mb3  = (const float*)d_in[17];
    const float* mW4  = (const float*)d_in[18];
    const float* mb4  = (const float*)d_in[19];

    char* ws = (char*)d_ws;
    size_t off = 0;
    auto alloc = [&](size_t bytes) -> void* {
        void* p = ws + off;
        off += (bytes + 255) & ~(size_t)255;
        return p;
    };
    int*   deg    = (int*)alloc((size_t)N_NODES * 4);
    int*   rs     = (int*)alloc((size_t)(N_NODES + 8) * 4);
    int*   cur    = (int*)alloc((size_t)N_NODES * 4);
    int*   bsum   = (int*)alloc((size_t)NB_SCAN * 4);
    int*   bpre   = (int*)alloc((size_t)NB_SCAN * 4);
    int*   eidc   = (int*)alloc((size_t)N_EDGES * 4);
    int*   srcc   = (int*)alloc((size_t)N_EDGES * 4);
    float* scorec = (float*)alloc((size_t)N_EDGES * 4);
    float* agg    = (float*)alloc((size_t)N_NODES * 64 * 4);
    _Float16* wsH = (_Float16*)alloc((size_t)WTOT * 2);
    _Float16* wsL = (_Float16*)alloc((size_t)WTOT * 2);
    _Float16* wkH = (_Float16*)alloc((size_t)KW2TOT * 2);
    _Float16* wkL = (_Float16*)alloc((size_t)KW2TOT * 2);
    _Float16* kwbuf = (_Float16*)alloc((size_t)N_EDGES * 64 * 2);

    hipMemsetAsync(deg, 0, (size_t)N_NODES * 4, stream);

    const int EB = (N_EDGES + 255) / 256;   // 3125
    const int GB = (N_NODES + 63) / 64;     // 782

    k_deg   <<<EB, 256, 0, stream>>>(dst, deg);
    k_bsum  <<<NB_SCAN, 256, 0, stream>>>(deg, bsum);
    k_bscan <<<1, 256, 0, stream>>>(bsum, bpre, rs);
    k_wr    <<<NB_SCAN, 256, 0, stream>>>(deg, bpre, rs, cur);
    k_fill  <<<EB, 256, 0, stream>>>(dst, src, off2, cur, eidc, srcc, scorec);
    k_wsplit<<<(WTOT + KW2TOT + 255) / 256, 256, 0, stream>>>(sW1, sW2, mW1, mW2, mW3, mW4,
                                                              kW2, wsH, wsL, wkH, wkL);

    k_kw <<<N_EDGES / 256, 256, 0, stream>>>(off2, eidc, kW1, kb1, wkH, wkL, kb2, kwbuf);
    k_agg<<<2048, 256, 0, stream>>>(scorec, srcc, rs, feat, kwbuf, agg);

    k_node<<<GB, 256, 0, stream>>>(feat, agg, wsH, wsL, sb1, sb2, mb1, mb2, mb3, mb4,
                                   (float*)d_out);
}